// Round 6
// baseline (3792.106 us; speedup 1.0000x reference)
//
#include <hip/hip_runtime.h>
#include <hip/hip_bf16.h>
#include <math.h>

typedef __hip_bfloat16 bf16;
typedef unsigned short ushort;
typedef __attribute__((ext_vector_type(8))) short bh8;
typedef __attribute__((ext_vector_type(4))) float f4;

#define HHW 48
#define PP  2304      // 48*48
#define MM  36864     // 16*2304

__device__ __forceinline__ float ldf(const float* p) { return *p; }
__device__ __forceinline__ float ldf(const bf16* p) { return __bfloat162float(*p); }
__device__ __forceinline__ void stf(float* p, float v) { *p = v; }
__device__ __forceinline__ void stf(bf16* p, float v) { *p = __float2bfloat16(v); }
__device__ __forceinline__ float b2f(ushort u) { return __uint_as_float((unsigned)u << 16); }
__device__ __forceinline__ ushort f2bu(float f) { bf16 h = __float2bfloat16(f); return *(ushort*)&h; }

// XOR swizzle: slot' = slot ^ ((row>>1)&3).  Verified conflict-free (r3: SQ_LDS_BANK_CONFLICT=0).
// READ side via loff(); WRITE side via pre-swizzled GLOBAL source address
// (global_load_lds writes LDS linearly: wave-uniform base + lane*16B).
__device__ __forceinline__ int loff(int row, int col8) {
    return row * 32 + (col8 ^ ((((row) >> 1) & 3) << 3));
}

// async global->LDS DMA, 16B per lane. gptr is PER-LANE, lptr must be wave-uniform.
__device__ __forceinline__ void gl_lds(const ushort* g, ushort* l) {
    __builtin_amdgcn_global_load_lds((const __attribute__((address_space(1))) void*)g,
                                     (__attribute__((address_space(3))) void*)l, 16, 0, 0);
}

// ---------------- prep kernels ----------------
// x (16,1024,48,48) f32 NCHW -> xb (36864, 1024) bf16 NHWC, 32x32 LDS tile transpose
__global__ void x2b_k(const float* __restrict__ x, bf16* __restrict__ xb) {
    __shared__ float tile[32][33];
    int b  = blockIdx.z;
    int c0 = blockIdx.y * 32;
    int p0 = blockIdx.x * 32;
    int lp = threadIdx.x & 31;
    int cg = threadIdx.x >> 5;   // 0..7
    #pragma unroll
    for (int j = 0; j < 4; ++j) {
        int c = cg * 4 + j;
        tile[c][lp] = x[((size_t)b * 1024 + c0 + c) * PP + p0 + lp];
    }
    __syncthreads();
    #pragma unroll
    for (int j = 0; j < 4; ++j) {
        int rp = cg * 4 + j;
        xb[((size_t)b * PP + p0 + rp) * 1024 + c0 + lp] = __float2bfloat16(tile[lp][rp]);
    }
}

// w (Cout, Cin, 3, 3) f32 -> wb (9, Cout, Cin) bf16
__global__ void w3b_k(const float* __restrict__ w, bf16* __restrict__ wb, int Cout, int Cin) {
    int idx = blockIdx.x * 256 + threadIdx.x;
    int n = Cout * Cin * 9;
    if (idx >= n) return;
    int kk  = idx / (Cout * Cin);
    int rem = idx - kk * Cout * Cin;
    int co  = rem / Cin;
    int ci  = rem - co * Cin;
    wb[idx] = __float2bfloat16(w[((size_t)co * Cin + ci) * 9 + kk]);
}

// flat f32 -> bf16
__global__ void f2b_k(const float* __restrict__ s, bf16* __restrict__ d, int n) {
    int i = blockIdx.x * 256 + threadIdx.x;
    if (i < n) d[i] = __float2bfloat16(s[i]);
}

// w (O, C) f32 -> wt (C, O) f32  (for cls GEMV)
__global__ void tw1_k(const float* __restrict__ w, float* __restrict__ wt, int O, int Cm) {
    int idx = blockIdx.x * 256 + threadIdx.x;
    int n = O * Cm;
    if (idx >= n) return;
    int o = idx / Cm;
    int c = idx - o * Cm;
    wt[c * O + o] = w[idx];
}

// ---------------- MFMA 3x3 conv, A-halo LDS reuse + global_load_lds staging ----------------
// r5-proven: M-tile 96, LDS 40 KB, conflicts=0, no spills, ~35% MfmaUtil.
template<typename OutT>
__global__ __launch_bounds__(256, 2)
void mconv3_k(const bf16* __restrict__ in, const bf16* __restrict__ wt,
              const float* __restrict__ bias, OutT* __restrict__ out,
              int Cin, int CinT, int ciOff, int Cout, int accum) {
    __shared__ ushort As[256 * 32];   // halo rows M0-49..M0+206 (194 used)
    __shared__ ushort Bs[384 * 32];   // 3 taps x 128 cout rows
    const ushort* inu = (const ushort*)in;
    const ushort* wtu = (const ushort*)wt;
    int tid = threadIdx.x;
    int N0 = blockIdx.x * 128;
    int M0 = blockIdx.y * 96;
    int sr = tid >> 2;            // 0..63 (LDS row within segment)
    int sc = (tid & 3) * 8;       // 0,8,16,24 (linear LDS slot)
    int wv = tid >> 6, lane = tid & 63;
    int wm = (wv & 1) * 48, wn = (wv >> 1) * 64;
    int l15 = lane & 15, quad = lane >> 4;

    // A staging: per-lane pre-swizzled global src, wave-uniform linear LDS dest
    const ushort* aptr[4];
    ushort* alds[4];
    #pragma unroll
    for (int j = 0; j < 4; ++j) {
        int row = j * 64 + sr;                         // LDS row
        int scs = sc ^ (((row >> 1) & 3) << 3);        // pre-swizzled col slot
        int gp = M0 - 49 + row;                        // global pixel row (clamped)
        gp = gp < 0 ? 0 : (gp > MM - 1 ? MM - 1 : gp);
        aptr[j] = inu + (size_t)gp * Cin + scs;
        alds[j] = As + (j * 64 + wv * 16) * 32;        // wave-uniform base
    }
    // B staging pointers for dy=0 taps; advance by dystep per dy
    const ushort* bptr[6];
    ushort* blds[6];
    #pragma unroll
    for (int j = 0; j < 6; ++j) {
        int row = j * 64 + sr;            // 0..383
        int scs = sc ^ (((row >> 1) & 3) << 3);
        int dxi = row >> 7;               // tap-within-dy 0..2
        int crow = row & 127;             // cout row within tile
        bptr[j] = wtu + ((size_t)dxi * Cout + N0 + crow) * CinT + ciOff + scs;
        blds[j] = Bs + (j * 64 + wv * 16) * 32;
    }
    size_t dystep = (size_t)3 * Cout * CinT;

    // per-lane (y,x) of the 3 A-rows this lane feeds to MFMA (fixed)
    int ry[3], rx[3];
    #pragma unroll
    for (int mi = 0; mi < 3; ++mi) {
        int r = (M0 + wm + mi * 16 + l15) % PP;
        ry[mi] = r / HHW;
        rx[mi] = r - ry[mi] * HHW;
    }

    f4 acc[3][4];
    #pragma unroll
    for (int i = 0; i < 3; ++i)
        #pragma unroll
        for (int j = 0; j < 4; ++j) acc[i][j] = (f4){0.f, 0.f, 0.f, 0.f};

    for (int c0 = 0; c0 < Cin; c0 += 32) {
        #pragma unroll
        for (int dy = 0; dy < 3; ++dy) {
            __syncthreads();                       // prior-phase readers done
            if (dy == 0) {
                #pragma unroll
                for (int j = 0; j < 4; ++j)
                    gl_lds(aptr[j] + c0, alds[j]);
            }
            #pragma unroll
            for (int j = 0; j < 6; ++j)
                gl_lds(bptr[j] + dy * dystep + c0, blds[j]);
            __syncthreads();                       // drains vmcnt -> LDS visible
            int dyp = dy - 1;
            bool vy[3];
            #pragma unroll
            for (int mi = 0; mi < 3; ++mi) vy[mi] = (unsigned)(ry[mi] + dyp) < (unsigned)HHW;
            #pragma unroll
            for (int dxi = 0; dxi < 3; ++dxi) {
                int dxp = dxi - 1;
                int sh = 49 + dyp * HHW + dxp;     // LDS row shift for this tap
                bh8 af[3], bfr[4];
                #pragma unroll
                for (int mi = 0; mi < 3; ++mi) {
                    bh8 a = {0, 0, 0, 0, 0, 0, 0, 0};
                    if (vy[mi] && (unsigned)(rx[mi] + dxp) < (unsigned)HHW)
                        a = *(const bh8*)(As + loff(wm + mi * 16 + l15 + sh, quad * 8));
                    af[mi] = a;
                }
                #pragma unroll
                for (int ni = 0; ni < 4; ++ni)
                    bfr[ni] = *(const bh8*)(Bs + loff(dxi * 128 + wn + ni * 16 + l15, quad * 8));
                #pragma unroll
                for (int mi = 0; mi < 3; ++mi)
                    #pragma unroll
                    for (int ni = 0; ni < 4; ++ni)
                        acc[mi][ni] = __builtin_amdgcn_mfma_f32_16x16x32_bf16(af[mi], bfr[ni], acc[mi][ni], 0, 0, 0);
            }
        }
    }

    // epilogue: C/D layout col=lane&15, row=quad*4+reg  [m89-verified]
    float bvn[4];
    #pragma unroll
    for (int ni = 0; ni < 4; ++ni)
        bvn[ni] = bias ? bias[N0 + wn + ni * 16 + l15] : 0.f;
    #pragma unroll
    for (int mi = 0; mi < 3; ++mi) {
        int mrow = M0 + wm + mi * 16 + quad * 4;
        #pragma unroll
        for (int ni = 0; ni < 4; ++ni) {
            int ncol = N0 + wn + ni * 16 + l15;
            #pragma unroll
            for (int r = 0; r < 4; ++r) {
                size_t oi = (size_t)(mrow + r) * Cout + ncol;
                float val = acc[mi][ni][r] + bvn[ni];
                if (accum) stf(&out[oi], ldf(&out[oi]) + val);
                else       stf(&out[oi], val);
            }
        }
    }
}

// ---------------- MFMA 1x1 conv (v-projection), gl_lds staged ----------------
// M-tile 96, N-tile 64, 12 KB LDS -> high occupancy; grid (Cout/64, 384).
template<typename OutT>
__global__ __launch_bounds__(256, 2)
void mc1_k(const bf16* __restrict__ in, const bf16* __restrict__ wt,
           const float* __restrict__ bias, OutT* __restrict__ out,
           int Cin, int Cout) {
    __shared__ ushort As[128 * 32];
    __shared__ ushort Bs[64 * 32];
    const ushort* inu = (const ushort*)in;
    const ushort* wtu = (const ushort*)wt;
    int tid = threadIdx.x;
    int N0 = blockIdx.x * 64;
    int M0 = blockIdx.y * 96;
    int sr = tid >> 2;
    int sc = (tid & 3) * 8;
    int scs = sc ^ (((sr >> 1) & 3) << 3);   // row ≡ sr (mod 64) so swizzle bits match loff
    int wv = tid >> 6, lane = tid & 63;
    int wm = (wv & 1) * 48, wn = (wv >> 1) * 32;
    int l15 = lane & 15, quad = lane >> 4;

    const ushort* aptr[2];
    #pragma unroll
    for (int j = 0; j < 2; ++j) {
        int gp = M0 + j * 64 + sr;                // rows 96..127 staged-but-unused
        gp = gp > MM - 1 ? MM - 1 : gp;
        aptr[j] = inu + (size_t)gp * Cin + scs;
    }
    const ushort* bptr = wtu + (size_t)(N0 + sr) * Cin + scs;
    ushort* alds0 = As + (wv * 16) * 32;
    ushort* alds1 = As + (64 + wv * 16) * 32;
    ushort* blds  = Bs + (wv * 16) * 32;

    f4 acc[3][2];
    #pragma unroll
    for (int i = 0; i < 3; ++i)
        #pragma unroll
        for (int j = 0; j < 2; ++j) acc[i][j] = (f4){0.f, 0.f, 0.f, 0.f};

    for (int c0 = 0; c0 < Cin; c0 += 32) {
        __syncthreads();
        gl_lds(aptr[0] + c0, alds0);
        gl_lds(aptr[1] + c0, alds1);
        gl_lds(bptr + c0, blds);
        __syncthreads();
        bh8 af[3], bfr[2];
        #pragma unroll
        for (int mi = 0; mi < 3; ++mi)
            af[mi] = *(const bh8*)(As + loff(wm + mi * 16 + l15, quad * 8));
        #pragma unroll
        for (int ni = 0; ni < 2; ++ni)
            bfr[ni] = *(const bh8*)(Bs + loff(wn + ni * 16 + l15, quad * 8));
        #pragma unroll
        for (int mi = 0; mi < 3; ++mi)
            #pragma unroll
            for (int ni = 0; ni < 2; ++ni)
                acc[mi][ni] = __builtin_amdgcn_mfma_f32_16x16x32_bf16(af[mi], bfr[ni], acc[mi][ni], 0, 0, 0);
    }

    float bvn[2];
    #pragma unroll
    for (int ni = 0; ni < 2; ++ni)
        bvn[ni] = bias ? bias[N0 + wn + ni * 16 + l15] : 0.f;
    #pragma unroll
    for (int mi = 0; mi < 3; ++mi) {
        int mrow = M0 + wm + mi * 16 + quad * 4;
        #pragma unroll
        for (int ni = 0; ni < 2; ++ni) {
            int ncol = N0 + wn + ni * 16 + l15;
            #pragma unroll
            for (int r = 0; r < 4; ++r) {
                size_t oi = (size_t)(mrow + r) * Cout + ncol;
                stf(&out[oi], acc[mi][ni][r] + bvn[ni]);
            }
        }
    }
}

// ---------------- batch norm ----------------
__global__ void zero_k(float* p, int n) {
    int i = blockIdx.x * 256 + threadIdx.x;
    if (i < n) p[i] = 0.f;
}

template<typename S>
__global__ void bn_stats_k(const S* __restrict__ src, float* __restrict__ sum,
                           float* __restrict__ sumsq, int Cout) {
    int t  = threadIdx.x;
    int c  = blockIdx.x * 64 + (t & 63);
    int pl = t >> 6;
    int p0 = blockIdx.y * 1024;
    float s = 0.f, ss = 0.f;
    for (int i = pl; i < 1024; i += 4) {
        float v = ldf(&src[(size_t)(p0 + i) * Cout + c]);
        s += v; ss += v * v;
    }
    __shared__ float ls[256], lss[256];
    ls[t] = s; lss[t] = ss;
    __syncthreads();
    if (t < 64) {
        s  = ls[t]  + ls[t + 64]  + ls[t + 128]  + ls[t + 192];
        ss = lss[t] + lss[t + 64] + lss[t + 128] + lss[t + 192];
        atomicAdd(&sum[c], s);
        atomicAdd(&sumsq[c], ss);
    }
}

__global__ void bn_fin_k(const float* __restrict__ sum, const float* __restrict__ sumsq,
                         const float* __restrict__ g, const float* __restrict__ b,
                         float* __restrict__ scale, float* __restrict__ shift, int Cout) {
    int c = blockIdx.x * 256 + threadIdx.x;
    if (c >= Cout) return;
    const float invM = 1.f / 36864.f;
    float mean = sum[c] * invM;
    float var  = sumsq[c] * invM - mean * mean;
    float inv  = 1.f / sqrtf(var + 1e-5f);
    scale[c] = g[c] * inv;
    shift[c] = b[c] - mean * g[c] * inv;
}

template<typename S, typename D>
__global__ void bn_apply_k(const S* __restrict__ src, const float* __restrict__ scale,
                           const float* __restrict__ shift, D* __restrict__ dst,
                           int cmask, int n) {
    int idx = blockIdx.x * 256 + threadIdx.x;
    if (idx >= n) return;
    int c = idx & cmask;
    float y = ldf(&src[idx]) * scale[c] + shift[c];
    stf(&dst[idx], fmaxf(y, 0.f));
}

// ---------------- conv1x1 q/k: 256ch -> 32, LDS-staged rows + native (O,C) weights ----------------
// block 256 thr = 8 pixels x 32 outputs; in rows staged via bh8 (no scalar global bf16 loads);
// weights read as float4 from the ORIGINAL (32,256) row-major tensor (L1-resident, 32 KB).
__global__ void conv1x1_k(const bf16* __restrict__ in, const float* __restrict__ w,
                          const float* __restrict__ bias, float* __restrict__ out) {
    __shared__ ushort irow[8][256];
    int t = threadIdx.x;
    int p0 = blockIdx.x * 8;
    {
        int r = t >> 5, c8 = (t & 31) * 8;
        *(bh8*)&irow[r][c8] = *(const bh8*)((const ushort*)in + (size_t)(p0 + r) * 256 + c8);
    }
    __syncthreads();
    int o = t & 31, pr = t >> 5;
    const float* wo = w + o * 256;
    float acc = 0.f;
    #pragma unroll
    for (int c = 0; c < 256; c += 8) {
        bh8 vv = *(const bh8*)&irow[pr][c];
        const float4* wp = (const float4*)(wo + c);
        float4 w0 = wp[0], w1 = wp[1];
        acc += b2f((ushort)vv[0]) * w0.x + b2f((ushort)vv[1]) * w0.y
             + b2f((ushort)vv[2]) * w0.z + b2f((ushort)vv[3]) * w0.w
             + b2f((ushort)vv[4]) * w1.x + b2f((ushort)vv[5]) * w1.y
             + b2f((ushort)vv[6]) * w1.z + b2f((ushort)vv[7]) * w1.w;
    }
    out[(size_t)(p0 + pr) * 32 + o] = acc + bias[o];
}

// ---------------- criss-cross spatial attention ----------------
__global__ void cc_logits_k(const float* __restrict__ q, const float* __restrict__ kk,
                            float* __restrict__ att) {
    int t = threadIdx.x;
    int p = blockIdx.x;
    int b = p / PP;
    int r = p - b * PP;
    int h = r / HHW;
    int w = r - h * HHW;
    __shared__ float qv[32];
    if (t < 32) qv[t] = q[p * 32 + t];
    __syncthreads();
    float val = -INFINITY;
    if (t < 48) {
        if (t != h) {
            const float* kr = kk + ((b * HHW + t) * HHW + w) * 32;
            float s = 0.f;
            #pragma unroll
            for (int c = 0; c < 32; ++c) s += qv[c] * kr[c];
            val = s;
        }
    } else if (t < 96) {
        const float* kr = kk + ((b * HHW + h) * HHW + (t - 48)) * 32;
        float s = 0.f;
        #pragma unroll
        for (int c = 0; c < 32; ++c) s += qv[c] * kr[c];
        val = s;
    }
    __shared__ float red[128];
    red[t] = val;
    __syncthreads();
    for (int st = 64; st > 0; st >>= 1) { if (t < st) red[t] = fmaxf(red[t], red[t + st]); __syncthreads(); }
    float m = red[0];
    __syncthreads();
    float e = (t < 96 && val != -INFINITY) ? expf(val - m) : 0.f;
    red[t] = e;
    __syncthreads();
    for (int st = 64; st > 0; st >>= 1) { if (t < st) red[t] += red[t + st]; __syncthreads(); }
    float inv = 1.f / red[0];
    if (t < 96) att[p * 96 + t] = e * inv;
}

// 128 threads x 2 channels per pixel; bf16 v (packed pair loads); in-place residual
__global__ void cc_out_k(const float* __restrict__ att, const bf16* __restrict__ v,
                         bf16* __restrict__ cc, const float* __restrict__ gptr) {
    int t = threadIdx.x;   // 128
    int p = blockIdx.x;
    __shared__ float a[96];
    if (t < 96) a[t] = att[p * 96 + t];
    __syncthreads();
    int b = p / PP;
    int r = p - b * PP;
    int h = r / HHW;
    int w = r - h * HHW;
    const ushort* vb = (const ushort*)v + (size_t)b * PP * 256;
    int c2 = t * 2;
    float a0 = 0.f, a1 = 0.f;
    #pragma unroll 4
    for (int g = 0; g < 48; ++g) {
        unsigned u = *(const unsigned*)&vb[(g * HHW + w) * 256 + c2];
        a0 += a[g] * b2f((ushort)u);
        a1 += a[g] * b2f((ushort)(u >> 16));
    }
    #pragma unroll 4
    for (int tt = 0; tt < 48; ++tt) {
        unsigned u = *(const unsigned*)&vb[(h * HHW + tt) * 256 + c2];
        a0 += a[48 + tt] * b2f((ushort)u);
        a1 += a[48 + tt] * b2f((ushort)(u >> 16));
    }
    float gamma = gptr[0];
    unsigned* cp = (unsigned*)((ushort*)cc + (size_t)p * 256 + c2);
    unsigned old = *cp;
    float r0 = gamma * a0 + b2f((ushort)old);
    float r1 = gamma * a1 + b2f((ushort)(old >> 16));
    *cp = (unsigned)f2bu(r0) | ((unsigned)f2bu(r1) << 16);
}

// ---------------- batch-grid ("my") attention ----------------
__global__ void gram_k(const float* __restrict__ q, const float* __restrict__ k,
                       float* __restrict__ G) {
    int t = threadIdx.x;
    int a  = blockIdx.x >> 4;
    int b2 = blockIdx.x & 15;
    const float* qa = q + a * 73728;
    const float* kb = k + b2 * 73728;
    float s = 0.f;
    for (int i = t; i < 73728; i += 256) s += qa[i] * kb[i];
    __shared__ float red[256];
    red[t] = s;
    __syncthreads();
    for (int st = 128; st > 0; st >>= 1) { if (t < st) red[t] += red[t + st]; __syncthreads(); }
    if (t == 0) G[blockIdx.x] = red[0];
}

__global__ void my_soft_k(const float* __restrict__ G, float* __restrict__ A) {
    int t = threadIdx.x;
    if (t >= 16) return;
    int i = t >> 2, j = t & 3;
    float l[8];
    for (int g = 0; g < 4; ++g) l[g] = (g == i) ? -INFINITY : G[t * 16 + g * 4 + j];
    for (int v = 0; v < 4; ++v) l[4 + v] = G[t * 16 + i * 4 + v];
    float m = l[0];
    for (int n = 1; n < 8; ++n) m = fmaxf(m, l[n]);
    float s = 0.f;
    for (int n = 0; n < 8; ++n) { l[n] = expf(l[n] - m); s += l[n]; }
    float inv = 1.f / s;
    for (int n = 0; n < 8; ++n) A[t * 8 + n] = l[n] * inv;
}

// bf16 v, 2 elements per thread (packed pair loads); grid 18432
__global__ void my_out_k(const float* __restrict__ A, const bf16* __restrict__ v,
                         bf16* __restrict__ my, const float* __restrict__ gptr) {
    int t = threadIdx.x;
    __shared__ float As[128];
    if (t < 128) As[t] = A[t];
    __syncthreads();
    size_t pidx = (size_t)blockIdx.x * 256 + t;   // pair index
    size_t idx = pidx * 2;
    int b = (int)(idx / 589824);
    int n = (int)(idx - (size_t)b * 589824);
    int i = b >> 2, j = b & 3;
    const ushort* vu = (const ushort*)v;
    float o0 = 0.f, o1 = 0.f;
    #pragma unroll
    for (int g = 0; g < 4; ++g) {
        unsigned u = *(const unsigned*)&vu[(size_t)(g * 4 + j) * 589824 + n];
        o0 += As[b * 8 + g] * b2f((ushort)u);
        o1 += As[b * 8 + g] * b2f((ushort)(u >> 16));
    }
    #pragma unroll
    for (int tt = 0; tt < 4; ++tt) {
        unsigned u = *(const unsigned*)&vu[(size_t)(i * 4 + tt) * 589824 + n];
        o0 += As[b * 8 + 4 + tt] * b2f((ushort)u);
        o1 += As[b * 8 + 4 + tt] * b2f((ushort)(u >> 16));
    }
    float gamma = gptr[0];
    unsigned* mp = (unsigned*)((ushort*)my + idx);
    unsigned old = *mp;
    float r0 = gamma * o0 + b2f((ushort)old);
    float r1 = gamma * o1 + b2f((ushort)(old >> 16));
    *mp = (unsigned)f2bu(r0) | ((unsigned)f2bu(r1) << 16);
}

// ---------------- classifier 1x1 -> f32 NCHW ----------------
__global__ void cls_k(const float* __restrict__ hsrc, const float* __restrict__ wt,
                      const float* __restrict__ bias, float* __restrict__ out) {
    int t = threadIdx.x;      // 128
    int p = blockIdx.x;
    __shared__ float hr[512];
    for (int i = t; i < 512; i += 128) hr[i] = hsrc[(size_t)p * 512 + i];
    __syncthreads();
    if (t < 21) {
        float acc = bias[t];
        #pragma unroll 4
        for (int c = 0; c < 512; ++c) acc += hr[c] * wt[c * 21 + t];
        int b = p / PP;
        int r = p - b * PP;
        out[(b * 21 + t) * PP + r] = acc;
    }
}

// ---------------- launch ----------------
extern "C" void kernel_launch(void* const* d_in, const int* in_sizes, int n_in,
                              void* d_out, int out_size, void* d_ws, size_t ws_size,
                              hipStream_t stream) {
    const float* x     = (const float*)d_in[0];
    const float* w_a   = (const float*)d_in[1];
    const float* g_a   = (const float*)d_in[2];
    const float* b_a   = (const float*)d_in[3];
    const float* ccq_w = (const float*)d_in[4];
    const float* ccq_b = (const float*)d_in[5];
    const float* cck_w = (const float*)d_in[6];
    const float* cck_b = (const float*)d_in[7];
    const float* ccv_w = (const float*)d_in[8];
    const float* ccv_b = (const float*)d_in[9];
    const float* cc_g  = (const float*)d_in[10];
    const float* w_b   = (const float*)d_in[11];
    const float* g_b   = (const float*)d_in[12];
    const float* b_b   = (const float*)d_in[13];
    const float* w_m1  = (const float*)d_in[14];
    const float* g_m1  = (const float*)d_in[15];
    const float* b_m1  = (const float*)d_in[16];
    const float* myq_w = (const float*)d_in[17];
    const float* myq_b = (const float*)d_in[18];
    const float* myk_w = (const float*)d_in[19];
    const float* myk_b = (const float*)d_in[20];
    const float* myv_w = (const float*)d_in[21];
    const float* myv_b = (const float*)d_in[22];
    const float* my_g  = (const float*)d_in[23];
    const float* w_m2  = (const float*)d_in[24];
    const float* g_m2  = (const float*)d_in[25];
    const float* b_m2  = (const float*)d_in[26];
    const float* w_c   = (const float*)d_in[27];
    const float* g_c   = (const float*)d_in[28];
    const float* b_c   = (const float*)d_in[29];
    const float* w_cls = (const float*)d_in[30];
    const float* b_cls = (const float*)d_in[31];
    float* out = (float*)d_out;

    char* ws = (char*)d_ws;
    size_t off = 0;
    bf16* cc  = (bf16*)(ws + off); off += (size_t)MM * 256 * 2;     // 18,874,368
    bf16* my  = (bf16*)(ws + off); off += (size_t)MM * 256 * 2;
    char* hx  = ws + off;          off += (size_t)MM * 256 * 4;     // 37,748,736 (f32 256 OR bf16 512)
    char* B   = ws + off;          off += (size_t)MM * 512 * 4;     // 75,497,472 multi-use
    bf16* wab  = (bf16*)(ws + off); off += 4718592;
    bf16* wm1b = (bf16*)(ws + off); off += 4718592;
    bf16* wbb  = (bf16*)(ws + off); off += 1179648;
    bf16* wm2b = (bf16*)(ws + off); off += 1179648;
    bf16* wcb  = (bf16*)(ws + off); off += 14155776;
    bf16* wvcb = (bf16*)(ws + off); off += 131072;
    bf16* wvmb = (bf16*)(ws + off); off += 131072;
    float* wclsT = (float*)(ws + off); off += 43008;
    float* stats = (float*)(ws + off); off += 16384;
    if (ws_size < off) return;   // ~177.3 MB
    float* ssum   = stats;
    float* ssumsq = stats + 512;
    float* sscale = stats + 1024;
    float* sshift = stats + 1536;
    float* G = stats + 2048;
    float* A = stats + 2048 + 256;

    // region B sub-views
    bf16*  xbf = (bf16*)B;                           // [36864,1024] early
    float* qb  = (float*)B;                          // attention phase
    float* kb  = (float*)(B + 4718592);
    bf16*  vbb = (bf16*)(B + 9437184);               // [36864,256] bf16
    float* att = (float*)(B + 47185920);             // [36864,96]  f32
    float* hxf = (float*)hx;                         // conv scratch f32 [36864,256]
    bf16*  hxb = (bf16*)hx;                          // concat accum bf16 [36864,512]
    float* hfin = (float*)B;                         // final BN output f32 [36864,512]

    // ---- prep ----
    x2b_k<<<dim3(72, 32, 16), 256, 0, stream>>>(x, xbf);
    w3b_k<<<9216, 256, 0, stream>>>(w_a,  wab,  256, 1024);
    w3b_k<<<9216, 256, 0, stream>>>(w_m1, wm1b, 256, 1024);
    w3b_k<<<2304, 256, 0, stream>>>(w_b,  wbb,  256, 256);
    w3b_k<<<2304, 256, 0, stream>>>(w_m2, wm2b, 256, 256);
    w3b_k<<<27648, 256, 0, stream>>>(w_c, wcb,  512, 1536);
    f2b_k<<<256, 256, 0, stream>>>(ccv_w, wvcb, 65536);
    f2b_k<<<256, 256, 0, stream>>>(myv_w, wvmb, 65536);
    tw1_k<<<42, 256, 0, stream>>>(w_cls, wclsT, 21, 512);

    auto bn = [&](auto* src, const float* g, const float* b, auto* dst, int Cout) {
        zero_k<<<4, 256, 0, stream>>>(ssum, 1024);
        bn_stats_k<<<dim3(Cout / 64, 36), 256, 0, stream>>>(src, ssum, ssumsq, Cout);
        bn_fin_k<<<(Cout + 255) / 256, 256, 0, stream>>>(ssum, ssumsq, g, b, sscale, sshift, Cout);
        int n = MM * Cout;
        bn_apply_k<<<n / 256, 256, 0, stream>>>(src, sscale, sshift, dst, Cout - 1, n);
    };

    // ---- initial convs (read xbf in B) ----
    mconv3_k<float><<<dim3(2, 384), 256, 0, stream>>>(xbf, wab, nullptr, hxf, 1024, 1024, 0, 256, 0);
    bn(hxf, g_a, b_a, cc, 256);
    mconv3_k<float><<<dim3(2, 384), 256, 0, stream>>>(xbf, wm1b, nullptr, hxf, 1024, 1024, 0, 256, 0);
    bn(hxf, g_m1, b_m1, my, 256);
    // concat x-part now (before B is reused): -> hx as bf16 [36864,512]
    mconv3_k<bf16><<<dim3(4, 384), 256, 0, stream>>>(xbf, wcb, nullptr, hxb, 1024, 1536, 0, 512, 0);

    // ---- criss-cross spatial attention x2 (bf16 cc in-place) ----
    for (int rec = 0; rec < 2; ++rec) {
        conv1x1_k<<<4608, 256, 0, stream>>>(cc, ccq_w, ccq_b, qb);
        conv1x1_k<<<4608, 256, 0, stream>>>(cc, cck_w, cck_b, kb);
        mc1_k<bf16><<<dim3(4, 384), 256, 0, stream>>>(cc, wvcb, ccv_b, vbb, 256, 256);
        cc_logits_k<<<MM, 128, 0, stream>>>(qb, kb, att);
        cc_out_k<<<MM, 128, 0, stream>>>(att, vbb, cc, cc_g);
    }

    // ---- batch-grid attention x2 (bf16 my in-place) ----
    for (int rec = 0; rec < 2; ++rec) {
        conv1x1_k<<<4608, 256, 0, stream>>>(my, myq_w, myq_b, qb);
        conv1x1_k<<<4608, 256, 0, stream>>>(my, myk_w, myk_b, kb);
        mc1_k<bf16><<<dim3(4, 384), 256, 0, stream>>>(my, wvmb, myv_b, vbb, 256, 256);
        gram_k<<<256, 256, 0, stream>>>(qb, kb, G);
        my_soft_k<<<1, 64, 0, stream>>>(G, A);
        my_out_k<<<18432, 256, 0, stream>>>(A, vbb, my, my_g);
    }

    // ---- post convs (outputs -> B as f32 scratch; B attention data dead) ----
    float* pscr = (float*)B;
    mconv3_k<float><<<dim3(2, 384), 256, 0, stream>>>(cc, wbb, nullptr, pscr, 256, 256, 0, 256, 0);
    bn(pscr, g_b, b_b, cc, 256);
    mconv3_k<float><<<dim3(2, 384), 256, 0, stream>>>(my, wm2b, nullptr, pscr, 256, 256, 0, 256, 0);
    bn(pscr, g_m2, b_m2, my, 256);

    // ---- concat cc/my parts accumulate into hxb ----
    mconv3_k<bf16><<<dim3(4, 384), 256, 0, stream>>>(cc, wcb, nullptr, hxb, 256, 1536, 1024, 512, 1);
    mconv3_k<bf16><<<dim3(4, 384), 256, 0, stream>>>(my, wcb, nullptr, hxb, 256, 1536, 1280, 512, 1);
    bn(hxb, g_c, b_c, hfin, 512);

    // ---- classifier ----
    cls_k<<<MM, 128, 0, stream>>>(hfin, wclsT, b_cls, out);
}

// Round 7
// 2791.957 us; speedup vs baseline: 1.3582x; 1.3582x over previous
//
#include <hip/hip_runtime.h>
#include <hip/hip_bf16.h>
#include <math.h>

typedef __hip_bfloat16 bf16;
typedef unsigned short ushort;
typedef __attribute__((ext_vector_type(8))) short bh8;
typedef __attribute__((ext_vector_type(4))) float f4;

#define HHW 48
#define PP  2304      // 48*48
#define MM  36864     // 16*2304

__device__ __forceinline__ float ldf(const float* p) { return *p; }
__device__ __forceinline__ float ldf(const bf16* p) { return __bfloat162float(*p); }
__device__ __forceinline__ void stf(float* p, float v) { *p = v; }
__device__ __forceinline__ void stf(bf16* p, float v) { *p = __float2bfloat16(v); }
__device__ __forceinline__ float b2f(ushort u) { return __uint_as_float((unsigned)u << 16); }
__device__ __forceinline__ ushort f2bu(float f) { bf16 h = __float2bfloat16(f); return *(ushort*)&h; }

// XOR swizzle: slot' = slot ^ ((row>>1)&3).  Verified conflict-free (r3: SQ_LDS_BANK_CONFLICT=0).
// READ side via loff(); WRITE side via pre-swizzled GLOBAL source address
// (global_load_lds writes LDS linearly: wave-uniform base + lane*16B).
__device__ __forceinline__ int loff(int row, int col8) {
    return row * 32 + (col8 ^ ((((row) >> 1) & 3) << 3));
}

// async global->LDS DMA, 16B per lane. gptr is PER-LANE, lptr must be wave-uniform.
__device__ __forceinline__ void gl_lds(const ushort* g, ushort* l) {
    __builtin_amdgcn_global_load_lds((const __attribute__((address_space(1))) void*)g,
                                     (__attribute__((address_space(3))) void*)l, 16, 0, 0);
}

// ---------------- prep kernels ----------------
// x (16,1024,48,48) f32 NCHW -> xb (36864, 1024) bf16 NHWC, 32x32 LDS tile transpose
__global__ void x2b_k(const float* __restrict__ x, bf16* __restrict__ xb) {
    __shared__ float tile[32][33];
    int b  = blockIdx.z;
    int c0 = blockIdx.y * 32;
    int p0 = blockIdx.x * 32;
    int lp = threadIdx.x & 31;
    int cg = threadIdx.x >> 5;   // 0..7
    #pragma unroll
    for (int j = 0; j < 4; ++j) {
        int c = cg * 4 + j;
        tile[c][lp] = x[((size_t)b * 1024 + c0 + c) * PP + p0 + lp];
    }
    __syncthreads();
    #pragma unroll
    for (int j = 0; j < 4; ++j) {
        int rp = cg * 4 + j;
        xb[((size_t)b * PP + p0 + rp) * 1024 + c0 + lp] = __float2bfloat16(tile[lp][rp]);
    }
}

// w (Cout, Cin, 3, 3) f32 -> wb (9, Cout, Cin) bf16
__global__ void w3b_k(const float* __restrict__ w, bf16* __restrict__ wb, int Cout, int Cin) {
    int idx = blockIdx.x * 256 + threadIdx.x;
    int n = Cout * Cin * 9;
    if (idx >= n) return;
    int kk  = idx / (Cout * Cin);
    int rem = idx - kk * Cout * Cin;
    int co  = rem / Cin;
    int ci  = rem - co * Cin;
    wb[idx] = __float2bfloat16(w[((size_t)co * Cin + ci) * 9 + kk]);
}

// combined qkv weight assembly: q(32,256)+k(32,256)+v(256,256) f32 -> [320,256] bf16
__global__ void wqkv_k(const float* __restrict__ qw, const float* __restrict__ kw,
                       const float* __restrict__ vw, bf16* __restrict__ dst) {
    int idx = blockIdx.x * 256 + threadIdx.x;
    if (idx >= 320 * 256) return;
    int r = idx >> 8, c = idx & 255;
    float v = (r < 32) ? qw[r * 256 + c] : (r < 64) ? kw[(r - 32) * 256 + c]
                                                    : vw[(size_t)(r - 64) * 256 + c];
    dst[idx] = __float2bfloat16(v);
}

// combined qkv bias: [320] f32
__global__ void cb_k(const float* __restrict__ qb, const float* __restrict__ kb,
                     const float* __restrict__ vb, float* __restrict__ dst) {
    int i = threadIdx.x;   // 320
    dst[i] = (i < 32) ? qb[i] : (i < 64) ? kb[i - 32] : vb[i - 64];
}

// w (O, C) f32 -> wt (C, O) f32  (for cls GEMV)
__global__ void tw1_k(const float* __restrict__ w, float* __restrict__ wt, int O, int Cm) {
    int idx = blockIdx.x * 256 + threadIdx.x;
    int n = O * Cm;
    if (idx >= n) return;
    int o = idx / Cm;
    int c = idx - o * Cm;
    wt[c * O + o] = w[idx];
}

// ---------------- MFMA 3x3 conv, A-halo LDS reuse + global_load_lds staging ----------------
// r5-proven: M-tile 96, LDS 40 KB, conflicts=0, no spills, ~35% MfmaUtil.
template<typename OutT>
__global__ __launch_bounds__(256, 2)
void mconv3_k(const bf16* __restrict__ in, const bf16* __restrict__ wt,
              const float* __restrict__ bias, OutT* __restrict__ out,
              int Cin, int CinT, int ciOff, int Cout, int accum) {
    __shared__ ushort As[256 * 32];   // halo rows M0-49..M0+206 (194 used)
    __shared__ ushort Bs[384 * 32];   // 3 taps x 128 cout rows
    const ushort* inu = (const ushort*)in;
    const ushort* wtu = (const ushort*)wt;
    int tid = threadIdx.x;
    int N0 = blockIdx.x * 128;
    int M0 = blockIdx.y * 96;
    int sr = tid >> 2;            // 0..63 (LDS row within segment)
    int sc = (tid & 3) * 8;       // 0,8,16,24 (linear LDS slot)
    int wv = tid >> 6, lane = tid & 63;
    int wm = (wv & 1) * 48, wn = (wv >> 1) * 64;
    int l15 = lane & 15, quad = lane >> 4;

    // A staging: per-lane pre-swizzled global src, wave-uniform linear LDS dest
    const ushort* aptr[4];
    ushort* alds[4];
    #pragma unroll
    for (int j = 0; j < 4; ++j) {
        int row = j * 64 + sr;                         // LDS row
        int scs = sc ^ (((row >> 1) & 3) << 3);        // pre-swizzled col slot
        int gp = M0 - 49 + row;                        // global pixel row (clamped)
        gp = gp < 0 ? 0 : (gp > MM - 1 ? MM - 1 : gp);
        aptr[j] = inu + (size_t)gp * Cin + scs;
        alds[j] = As + (j * 64 + wv * 16) * 32;        // wave-uniform base
    }
    // B staging pointers for dy=0 taps; advance by dystep per dy
    const ushort* bptr[6];
    ushort* blds[6];
    #pragma unroll
    for (int j = 0; j < 6; ++j) {
        int row = j * 64 + sr;            // 0..383
        int scs = sc ^ (((row >> 1) & 3) << 3);
        int dxi = row >> 7;               // tap-within-dy 0..2
        int crow = row & 127;             // cout row within tile
        bptr[j] = wtu + ((size_t)dxi * Cout + N0 + crow) * CinT + ciOff + scs;
        blds[j] = Bs + (j * 64 + wv * 16) * 32;
    }
    size_t dystep = (size_t)3 * Cout * CinT;

    // per-lane (y,x) of the 3 A-rows this lane feeds to MFMA (fixed)
    int ry[3], rx[3];
    #pragma unroll
    for (int mi = 0; mi < 3; ++mi) {
        int r = (M0 + wm + mi * 16 + l15) % PP;
        ry[mi] = r / HHW;
        rx[mi] = r - ry[mi] * HHW;
    }

    f4 acc[3][4];
    #pragma unroll
    for (int i = 0; i < 3; ++i)
        #pragma unroll
        for (int j = 0; j < 4; ++j) acc[i][j] = (f4){0.f, 0.f, 0.f, 0.f};

    for (int c0 = 0; c0 < Cin; c0 += 32) {
        #pragma unroll
        for (int dy = 0; dy < 3; ++dy) {
            __syncthreads();                       // prior-phase readers done
            if (dy == 0) {
                #pragma unroll
                for (int j = 0; j < 4; ++j)
                    gl_lds(aptr[j] + c0, alds[j]);
            }
            #pragma unroll
            for (int j = 0; j < 6; ++j)
                gl_lds(bptr[j] + dy * dystep + c0, blds[j]);
            __syncthreads();                       // drains vmcnt -> LDS visible
            int dyp = dy - 1;
            bool vy[3];
            #pragma unroll
            for (int mi = 0; mi < 3; ++mi) vy[mi] = (unsigned)(ry[mi] + dyp) < (unsigned)HHW;
            #pragma unroll
            for (int dxi = 0; dxi < 3; ++dxi) {
                int dxp = dxi - 1;
                int sh = 49 + dyp * HHW + dxp;     // LDS row shift for this tap
                bh8 af[3], bfr[4];
                #pragma unroll
                for (int mi = 0; mi < 3; ++mi) {
                    bh8 a = {0, 0, 0, 0, 0, 0, 0, 0};
                    if (vy[mi] && (unsigned)(rx[mi] + dxp) < (unsigned)HHW)
                        a = *(const bh8*)(As + loff(wm + mi * 16 + l15 + sh, quad * 8));
                    af[mi] = a;
                }
                #pragma unroll
                for (int ni = 0; ni < 4; ++ni)
                    bfr[ni] = *(const bh8*)(Bs + loff(dxi * 128 + wn + ni * 16 + l15, quad * 8));
                #pragma unroll
                for (int mi = 0; mi < 3; ++mi)
                    #pragma unroll
                    for (int ni = 0; ni < 4; ++ni)
                        acc[mi][ni] = __builtin_amdgcn_mfma_f32_16x16x32_bf16(af[mi], bfr[ni], acc[mi][ni], 0, 0, 0);
            }
        }
    }

    // epilogue: C/D layout col=lane&15, row=quad*4+reg  [m89-verified]
    float bvn[4];
    #pragma unroll
    for (int ni = 0; ni < 4; ++ni)
        bvn[ni] = bias ? bias[N0 + wn + ni * 16 + l15] : 0.f;
    #pragma unroll
    for (int mi = 0; mi < 3; ++mi) {
        int mrow = M0 + wm + mi * 16 + quad * 4;
        #pragma unroll
        for (int ni = 0; ni < 4; ++ni) {
            int ncol = N0 + wn + ni * 16 + l15;
            #pragma unroll
            for (int r = 0; r < 4; ++r) {
                size_t oi = (size_t)(mrow + r) * Cout + ncol;
                float val = acc[mi][ni][r] + bvn[ni];
                if (accum) stf(&out[oi], ldf(&out[oi]) + val);
                else       stf(&out[oi], val);
            }
        }
    }
}

// ---------------- fused qkv MFMA GEMM: [36864,256] x [320,256]^T ----------------
// mc1_k structure (M-tile 96, N-tile 64, 12 KB LDS, gl_lds + XOR swizzle).
// Epilogue routes cols 0-31 -> q (f32 [M,32]), 32-63 -> k (f32 [M,32]),
// 64-319 -> v (bf16 [M,256]). Branch is uniform per 16-col group (no divergence).
__global__ __launch_bounds__(256, 2)
void mqkv_k(const bf16* __restrict__ in, const bf16* __restrict__ wt,
            const float* __restrict__ bias, float* __restrict__ qo,
            float* __restrict__ ko, bf16* __restrict__ vo) {
    __shared__ ushort As[128 * 32];
    __shared__ ushort Bs[64 * 32];
    const int Cin = 256;
    const ushort* inu = (const ushort*)in;
    const ushort* wtu = (const ushort*)wt;
    int tid = threadIdx.x;
    int N0 = blockIdx.x * 64;       // 0..4 -> cols 0..319
    int M0 = blockIdx.y * 96;
    int sr = tid >> 2;
    int sc = (tid & 3) * 8;
    int scs = sc ^ (((sr >> 1) & 3) << 3);   // row ≡ sr (mod 64): swizzle bits match loff
    int wv = tid >> 6, lane = tid & 63;
    int wm = (wv & 1) * 48, wn = (wv >> 1) * 32;
    int l15 = lane & 15, quad = lane >> 4;

    const ushort* aptr[2];
    #pragma unroll
    for (int j = 0; j < 2; ++j) {
        int gp = M0 + j * 64 + sr;                // rows 96..127 staged-but-unused
        gp = gp > MM - 1 ? MM - 1 : gp;
        aptr[j] = inu + (size_t)gp * Cin + scs;
    }
    const ushort* bptr = wtu + (size_t)(N0 + sr) * Cin + scs;
    ushort* alds0 = As + (wv * 16) * 32;
    ushort* alds1 = As + (64 + wv * 16) * 32;
    ushort* blds  = Bs + (wv * 16) * 32;

    f4 acc[3][2];
    #pragma unroll
    for (int i = 0; i < 3; ++i)
        #pragma unroll
        for (int j = 0; j < 2; ++j) acc[i][j] = (f4){0.f, 0.f, 0.f, 0.f};

    for (int c0 = 0; c0 < Cin; c0 += 32) {
        __syncthreads();
        gl_lds(aptr[0] + c0, alds0);
        gl_lds(aptr[1] + c0, alds1);
        gl_lds(bptr + c0, blds);
        __syncthreads();
        bh8 af[3], bfr[2];
        #pragma unroll
        for (int mi = 0; mi < 3; ++mi)
            af[mi] = *(const bh8*)(As + loff(wm + mi * 16 + l15, quad * 8));
        #pragma unroll
        for (int ni = 0; ni < 2; ++ni)
            bfr[ni] = *(const bh8*)(Bs + loff(wn + ni * 16 + l15, quad * 8));
        #pragma unroll
        for (int mi = 0; mi < 3; ++mi)
            #pragma unroll
            for (int ni = 0; ni < 2; ++ni)
                acc[mi][ni] = __builtin_amdgcn_mfma_f32_16x16x32_bf16(af[mi], bfr[ni], acc[mi][ni], 0, 0, 0);
    }

    float bvn[2];
    #pragma unroll
    for (int ni = 0; ni < 2; ++ni)
        bvn[ni] = bias[N0 + wn + ni * 16 + l15];
    #pragma unroll
    for (int mi = 0; mi < 3; ++mi) {
        int mrow = M0 + wm + mi * 16 + quad * 4;
        #pragma unroll
        for (int ni = 0; ni < 2; ++ni) {
            int ncol = N0 + wn + ni * 16 + l15;
            #pragma unroll
            for (int r = 0; r < 4; ++r) {
                float val = acc[mi][ni][r] + bvn[ni];
                if (ncol < 32)
                    qo[(size_t)(mrow + r) * 32 + ncol] = val;
                else if (ncol < 64)
                    ko[(size_t)(mrow + r) * 32 + ncol - 32] = val;
                else
                    vo[(size_t)(mrow + r) * 256 + ncol - 64] = __float2bfloat16(val);
            }
        }
    }
}

// ---------------- batch norm ----------------
__global__ void zero_k(float* p, int n) {
    int i = blockIdx.x * 256 + threadIdx.x;
    if (i < n) p[i] = 0.f;
}

template<typename S>
__global__ void bn_stats_k(const S* __restrict__ src, float* __restrict__ sum,
                           float* __restrict__ sumsq, int Cout) {
    int t  = threadIdx.x;
    int c  = blockIdx.x * 64 + (t & 63);
    int pl = t >> 6;
    int p0 = blockIdx.y * 1024;
    float s = 0.f, ss = 0.f;
    for (int i = pl; i < 1024; i += 4) {
        float v = ldf(&src[(size_t)(p0 + i) * Cout + c]);
        s += v; ss += v * v;
    }
    __shared__ float ls[256], lss[256];
    ls[t] = s; lss[t] = ss;
    __syncthreads();
    if (t < 64) {
        s  = ls[t]  + ls[t + 64]  + ls[t + 128]  + ls[t + 192];
        ss = lss[t] + lss[t + 64] + lss[t + 128] + lss[t + 192];
        atomicAdd(&sum[c], s);
        atomicAdd(&sumsq[c], ss);
    }
}

__global__ void bn_fin_k(const float* __restrict__ sum, const float* __restrict__ sumsq,
                         const float* __restrict__ g, const float* __restrict__ b,
                         float* __restrict__ scale, float* __restrict__ shift, int Cout) {
    int c = blockIdx.x * 256 + threadIdx.x;
    if (c >= Cout) return;
    const float invM = 1.f / 36864.f;
    float mean = sum[c] * invM;
    float var  = sumsq[c] * invM - mean * mean;
    float inv  = 1.f / sqrtf(var + 1e-5f);
    scale[c] = g[c] * inv;
    shift[c] = b[c] - mean * g[c] * inv;
}

template<typename S, typename D>
__global__ void bn_apply_k(const S* __restrict__ src, const float* __restrict__ scale,
                           const float* __restrict__ shift, D* __restrict__ dst,
                           int cmask, int n) {
    int idx = blockIdx.x * 256 + threadIdx.x;
    if (idx >= n) return;
    int c = idx & cmask;
    float y = ldf(&src[idx]) * scale[c] + shift[c];
    stf(&dst[idx], fmaxf(y, 0.f));
}

// ---------------- criss-cross spatial attention ----------------
__global__ void cc_logits_k(const float* __restrict__ q, const float* __restrict__ kk,
                            float* __restrict__ att) {
    int t = threadIdx.x;
    int p = blockIdx.x;
    int b = p / PP;
    int r = p - b * PP;
    int h = r / HHW;
    int w = r - h * HHW;
    __shared__ float qv[32];
    if (t < 32) qv[t] = q[p * 32 + t];
    __syncthreads();
    float val = -INFINITY;
    if (t < 48) {
        if (t != h) {
            const float* kr = kk + ((b * HHW + t) * HHW + w) * 32;
            float s = 0.f;
            #pragma unroll
            for (int c = 0; c < 32; ++c) s += qv[c] * kr[c];
            val = s;
        }
    } else if (t < 96) {
        const float* kr = kk + ((b * HHW + h) * HHW + (t - 48)) * 32;
        float s = 0.f;
        #pragma unroll
        for (int c = 0; c < 32; ++c) s += qv[c] * kr[c];
        val = s;
    }
    __shared__ float red[128];
    red[t] = val;
    __syncthreads();
    for (int st = 64; st > 0; st >>= 1) { if (t < st) red[t] = fmaxf(red[t], red[t + st]); __syncthreads(); }
    float m = red[0];
    __syncthreads();
    float e = (t < 96 && val != -INFINITY) ? expf(val - m) : 0.f;
    red[t] = e;
    __syncthreads();
    for (int st = 64; st > 0; st >>= 1) { if (t < st) red[t] += red[t + st]; __syncthreads(); }
    float inv = 1.f / red[0];
    if (t < 96) att[p * 96 + t] = e * inv;
}

// 128 threads x 2 channels per pixel; bf16 v (packed pair loads); in-place residual
__global__ void cc_out_k(const float* __restrict__ att, const bf16* __restrict__ v,
                         bf16* __restrict__ cc, const float* __restrict__ gptr) {
    int t = threadIdx.x;   // 128
    int p = blockIdx.x;
    __shared__ float a[96];
    if (t < 96) a[t] = att[p * 96 + t];
    __syncthreads();
    int b = p / PP;
    int r = p - b * PP;
    int h = r / HHW;
    int w = r - h * HHW;
    const ushort* vb = (const ushort*)v + (size_t)b * PP * 256;
    int c2 = t * 2;
    float a0 = 0.f, a1 = 0.f;
    #pragma unroll 4
    for (int g = 0; g < 48; ++g) {
        unsigned u = *(const unsigned*)&vb[(g * HHW + w) * 256 + c2];
        a0 += a[g] * b2f((ushort)u);
        a1 += a[g] * b2f((ushort)(u >> 16));
    }
    #pragma unroll 4
    for (int tt = 0; tt < 48; ++tt) {
        unsigned u = *(const unsigned*)&vb[(h * HHW + tt) * 256 + c2];
        a0 += a[48 + tt] * b2f((ushort)u);
        a1 += a[48 + tt] * b2f((ushort)(u >> 16));
    }
    float gamma = gptr[0];
    unsigned* cp = (unsigned*)((ushort*)cc + (size_t)p * 256 + c2);
    unsigned old = *cp;
    float r0 = gamma * a0 + b2f((ushort)old);
    float r1 = gamma * a1 + b2f((ushort)(old >> 16));
    *cp = (unsigned)f2bu(r0) | ((unsigned)f2bu(r1) << 16);
}

// ---------------- batch-grid ("my") attention ----------------
__global__ void gram_k(const float* __restrict__ q, const float* __restrict__ k,
                       float* __restrict__ G) {
    int t = threadIdx.x;
    int a  = blockIdx.x >> 4;
    int b2 = blockIdx.x & 15;
    const float* qa = q + a * 73728;
    const float* kb = k + b2 * 73728;
    float s = 0.f;
    for (int i = t; i < 73728; i += 256) s += qa[i] * kb[i];
    __shared__ float red[256];
    red[t] = s;
    __syncthreads();
    for (int st = 128; st > 0; st >>= 1) { if (t < st) red[t] += red[t + st]; __syncthreads(); }
    if (t == 0) G[blockIdx.x] = red[0];
}

__global__ void my_soft_k(const float* __restrict__ G, float* __restrict__ A) {
    int t = threadIdx.x;
    if (t >= 16) return;
    int i = t >> 2, j = t & 3;
    float l[8];
    for (int g = 0; g < 4; ++g) l[g] = (g == i) ? -INFINITY : G[t * 16 + g * 4 + j];
    for (int v = 0; v < 4; ++v) l[4 + v] = G[t * 16 + i * 4 + v];
    float m = l[0];
    for (int n = 1; n < 8; ++n) m = fmaxf(m, l[n]);
    float s = 0.f;
    for (int n = 0; n < 8; ++n) { l[n] = expf(l[n] - m); s += l[n]; }
    float inv = 1.f / s;
    for (int n = 0; n < 8; ++n) A[t * 8 + n] = l[n] * inv;
}

// bf16 v, 2 elements per thread (packed pair loads); grid 18432
__global__ void my_out_k(const float* __restrict__ A, const bf16* __restrict__ v,
                         bf16* __restrict__ my, const float* __restrict__ gptr) {
    int t = threadIdx.x;
    __shared__ float As[128];
    if (t < 128) As[t] = A[t];
    __syncthreads();
    size_t pidx = (size_t)blockIdx.x * 256 + t;   // pair index
    size_t idx = pidx * 2;
    int b = (int)(idx / 589824);
    int n = (int)(idx - (size_t)b * 589824);
    int i = b >> 2, j = b & 3;
    const ushort* vu = (const ushort*)v;
    float o0 = 0.f, o1 = 0.f;
    #pragma unroll
    for (int g = 0; g < 4; ++g) {
        unsigned u = *(const unsigned*)&vu[(size_t)(g * 4 + j) * 589824 + n];
        o0 += As[b * 8 + g] * b2f((ushort)u);
        o1 += As[b * 8 + g] * b2f((ushort)(u >> 16));
    }
    #pragma unroll
    for (int tt = 0; tt < 4; ++tt) {
        unsigned u = *(const unsigned*)&vu[(size_t)(i * 4 + tt) * 589824 + n];
        o0 += As[b * 8 + 4 + tt] * b2f((ushort)u);
        o1 += As[b * 8 + 4 + tt] * b2f((ushort)(u >> 16));
    }
    float gamma = gptr[0];
    unsigned* mp = (unsigned*)((ushort*)my + idx);
    unsigned old = *mp;
    float r0 = gamma * o0 + b2f((ushort)old);
    float r1 = gamma * o1 + b2f((ushort)(old >> 16));
    *mp = (unsigned)f2bu(r0) | ((unsigned)f2bu(r1) << 16);
}

// ---------------- classifier 1x1 -> f32 NCHW ----------------
__global__ void cls_k(const float* __restrict__ hsrc, const float* __restrict__ wt,
                      const float* __restrict__ bias, float* __restrict__ out) {
    int t = threadIdx.x;      // 128
    int p = blockIdx.x;
    __shared__ float hr[512];
    for (int i = t; i < 512; i += 128) hr[i] = hsrc[(size_t)p * 512 + i];
    __syncthreads();
    if (t < 21) {
        float acc = bias[t];
        #pragma unroll 4
        for (int c = 0; c < 512; ++c) acc += hr[c] * wt[c * 21 + t];
        int b = p / PP;
        int r = p - b * PP;
        out[(b * 21 + t) * PP + r] = acc;
    }
}

// ---------------- launch ----------------
extern "C" void kernel_launch(void* const* d_in, const int* in_sizes, int n_in,
                              void* d_out, int out_size, void* d_ws, size_t ws_size,
                              hipStream_t stream) {
    const float* x     = (const float*)d_in[0];
    const float* w_a   = (const float*)d_in[1];
    const float* g_a   = (const float*)d_in[2];
    const float* b_a   = (const float*)d_in[3];
    const float* ccq_w = (const float*)d_in[4];
    const float* ccq_b = (const float*)d_in[5];
    const float* cck_w = (const float*)d_in[6];
    const float* cck_b = (const float*)d_in[7];
    const float* ccv_w = (const float*)d_in[8];
    const float* ccv_b = (const float*)d_in[9];
    const float* cc_g  = (const float*)d_in[10];
    const float* w_b   = (const float*)d_in[11];
    const float* g_b   = (const float*)d_in[12];
    const float* b_b   = (const float*)d_in[13];
    const float* w_m1  = (const float*)d_in[14];
    const float* g_m1  = (const float*)d_in[15];
    const float* b_m1  = (const float*)d_in[16];
    const float* myq_w = (const float*)d_in[17];
    const float* myq_b = (const float*)d_in[18];
    const float* myk_w = (const float*)d_in[19];
    const float* myk_b = (const float*)d_in[20];
    const float* myv_w = (const float*)d_in[21];
    const float* myv_b = (const float*)d_in[22];
    const float* my_g  = (const float*)d_in[23];
    const float* w_m2  = (const float*)d_in[24];
    const float* g_m2  = (const float*)d_in[25];
    const float* b_m2  = (const float*)d_in[26];
    const float* w_c   = (const float*)d_in[27];
    const float* g_c   = (const float*)d_in[28];
    const float* b_c   = (const float*)d_in[29];
    const float* w_cls = (const float*)d_in[30];
    const float* b_cls = (const float*)d_in[31];
    float* out = (float*)d_out;

    char* ws = (char*)d_ws;
    size_t off = 0;
    bf16* cc  = (bf16*)(ws + off); off += (size_t)MM * 256 * 2;     // 18,874,368
    bf16* my  = (bf16*)(ws + off); off += (size_t)MM * 256 * 2;
    char* hx  = ws + off;          off += (size_t)MM * 256 * 4;     // 37,748,736 (f32 256 OR bf16 512)
    char* B   = ws + off;          off += (size_t)MM * 512 * 4;     // 75,497,472 multi-use
    bf16* wab  = (bf16*)(ws + off); off += 4718592;
    bf16* wm1b = (bf16*)(ws + off); off += 4718592;
    bf16* wbb  = (bf16*)(ws + off); off += 1179648;
    bf16* wm2b = (bf16*)(ws + off); off += 1179648;
    bf16* wcb  = (bf16*)(ws + off); off += 14155776;
    bf16* wqc  = (bf16*)(ws + off); off += 163840;    // cc qkv combined [320,256] bf16
    bf16* wqm  = (bf16*)(ws + off); off += 163840;    // my qkv combined
    float* wclsT = (float*)(ws + off); off += 43008;
    float* stats = (float*)(ws + off); off += 16384;
    if (ws_size < off) return;   // ~177.4 MB (within r0 footprint: tw buffers dropped)
    float* ssum   = stats;
    float* ssumsq = stats + 512;
    float* sscale = stats + 1024;
    float* sshift = stats + 1536;
    float* G = stats + 2048;
    float* A = stats + 2048 + 256;
    float* bqc = stats + 2560;   // [320] combined cc bias
    float* bqm = stats + 2880;   // [320] combined my bias

    // region B sub-views
    bf16*  xbf = (bf16*)B;                           // [36864,1024] early
    float* qb  = (float*)B;                          // attention phase [36864,32] f32
    float* kb  = (float*)(B + 4718592);
    bf16*  vbb = (bf16*)(B + 9437184);               // [36864,256] bf16
    float* att = (float*)(B + 47185920);             // [36864,96]  f32
    float* hxf = (float*)hx;                         // conv scratch f32 [36864,256]
    bf16*  hxb = (bf16*)hx;                          // concat accum bf16 [36864,512]
    float* hfin = (float*)B;                         // final BN output f32 [36864,512]

    // ---- prep ----
    x2b_k<<<dim3(72, 32, 16), 256, 0, stream>>>(x, xbf);
    w3b_k<<<9216, 256, 0, stream>>>(w_a,  wab,  256, 1024);
    w3b_k<<<9216, 256, 0, stream>>>(w_m1, wm1b, 256, 1024);
    w3b_k<<<2304, 256, 0, stream>>>(w_b,  wbb,  256, 256);
    w3b_k<<<2304, 256, 0, stream>>>(w_m2, wm2b, 256, 256);
    w3b_k<<<27648, 256, 0, stream>>>(w_c, wcb,  512, 1536);
    wqkv_k<<<320, 256, 0, stream>>>(ccq_w, cck_w, ccv_w, wqc);
    wqkv_k<<<320, 256, 0, stream>>>(myq_w, myk_w, myv_w, wqm);
    cb_k<<<1, 320, 0, stream>>>(ccq_b, cck_b, ccv_b, bqc);
    cb_k<<<1, 320, 0, stream>>>(myq_b, myk_b, myv_b, bqm);
    tw1_k<<<42, 256, 0, stream>>>(w_cls, wclsT, 21, 512);

    auto bn = [&](auto* src, const float* g, const float* b, auto* dst, int Cout) {
        zero_k<<<4, 256, 0, stream>>>(ssum, 1024);
        bn_stats_k<<<dim3(Cout / 64, 36), 256, 0, stream>>>(src, ssum, ssumsq, Cout);
        bn_fin_k<<<(Cout + 255) / 256, 256, 0, stream>>>(ssum, ssumsq, g, b, sscale, sshift, Cout);
        int n = MM * Cout;
        bn_apply_k<<<n / 256, 256, 0, stream>>>(src, sscale, sshift, dst, Cout - 1, n);
    };

    // ---- initial convs (read xbf in B) ----
    mconv3_k<float><<<dim3(2, 384), 256, 0, stream>>>(xbf, wab, nullptr, hxf, 1024, 1024, 0, 256, 0);
    bn(hxf, g_a, b_a, cc, 256);
    mconv3_k<float><<<dim3(2, 384), 256, 0, stream>>>(xbf, wm1b, nullptr, hxf, 1024, 1024, 0, 256, 0);
    bn(hxf, g_m1, b_m1, my, 256);
    // concat x-part now (before B is reused): -> hx as bf16 [36864,512]
    mconv3_k<bf16><<<dim3(4, 384), 256, 0, stream>>>(xbf, wcb, nullptr, hxb, 1024, 1536, 0, 512, 0);

    // ---- criss-cross spatial attention x2 (bf16 cc in-place) ----
    for (int rec = 0; rec < 2; ++rec) {
        mqkv_k<<<dim3(5, 384), 256, 0, stream>>>(cc, wqc, bqc, qb, kb, vbb);
        cc_logits_k<<<MM, 128, 0, stream>>>(qb, kb, att);
        cc_out_k<<<MM, 128, 0, stream>>>(att, vbb, cc, cc_g);
    }

    // ---- batch-grid attention x2 (bf16 my in-place) ----
    for (int rec = 0; rec < 2; ++rec) {
        mqkv_k<<<dim3(5, 384), 256, 0, stream>>>(my, wqm, bqm, qb, kb, vbb);
        gram_k<<<256, 256, 0, stream>>>(qb, kb, G);
        my_soft_k<<<1, 64, 0, stream>>>(G, A);
        my_out_k<<<18432, 256, 0, stream>>>(A, vbb, my, my_g);
    }

    // ---- post convs (outputs -> B as f32 scratch; B attention data dead) ----
    float* pscr = (float*)B;
    mconv3_k<float><<<dim3(2, 384), 256, 0, stream>>>(cc, wbb, nullptr, pscr, 256, 256, 0, 256, 0);
    bn(pscr, g_b, b_b, cc, 256);
    mconv3_k<float><<<dim3(2, 384), 256, 0, stream>>>(my, wm2b, nullptr, pscr, 256, 256, 0, 256, 0);
    bn(pscr, g_m2, b_m2, my, 256);

    // ---- concat cc/my parts accumulate into hxb ----
    mconv3_k<bf16><<<dim3(4, 384), 256, 0, stream>>>(cc, wcb, nullptr, hxb, 256, 1536, 1024, 512, 1);
    mconv3_k<bf16><<<dim3(4, 384), 256, 0, stream>>>(my, wcb, nullptr, hxb, 256, 1536, 1280, 512, 1);
    bn(hxb, g_c, b_c, hfin, 512);

    // ---- classifier ----
    cls_k<<<MM, 128, 0, stream>>>(hfin, wclsT, b_cls, out);
}

// Round 9
// 2523.894 us; speedup vs baseline: 1.5025x; 1.1062x over previous
//
#include <hip/hip_runtime.h>
#include <hip/hip_bf16.h>
#include <math.h>

typedef __hip_bfloat16 bf16;
typedef unsigned short ushort;
typedef __attribute__((ext_vector_type(8))) short bh8;
typedef __attribute__((ext_vector_type(4))) float f4;

#define HHW 48
#define PP  2304      // 48*48
#define MM  36864     // 16*2304

__device__ __forceinline__ float ldf(const float* p) { return *p; }
__device__ __forceinline__ float ldf(const bf16* p) { return __bfloat162float(*p); }
__device__ __forceinline__ void stf(float* p, float v) { *p = v; }
__device__ __forceinline__ void stf(bf16* p, float v) { *p = __float2bfloat16(v); }
__device__ __forceinline__ float b2f(ushort u) { return __uint_as_float((unsigned)u << 16); }
__device__ __forceinline__ ushort f2bu(float f) { bf16 h = __float2bfloat16(f); return *(ushort*)&h; }

// XOR swizzle: slot' = slot ^ ((row>>1)&3).  Verified conflict-free (r3: SQ_LDS_BANK_CONFLICT=0).
// READ side via loff(); WRITE side via pre-swizzled GLOBAL source address
// (global_load_lds writes LDS linearly: wave-uniform base + lane*16B).
__device__ __forceinline__ int loff(int row, int col8) {
    return row * 32 + (col8 ^ ((((row) >> 1) & 3) << 3));
}

// async global->LDS DMA, 16B per lane. gptr is PER-LANE, lptr must be wave-uniform.
__device__ __forceinline__ void gl_lds(const ushort* g, ushort* l) {
    __builtin_amdgcn_global_load_lds((const __attribute__((address_space(1))) void*)g,
                                     (__attribute__((address_space(3))) void*)l, 16, 0, 0);
}

// ---------------- prep kernels ----------------
// x (16,1024,48,48) f32 NCHW -> xb (36864, 1024) bf16 NHWC, 32x32 LDS tile transpose
__global__ void x2b_k(const float* __restrict__ x, bf16* __restrict__ xb) {
    __shared__ float tile[32][33];
    int b  = blockIdx.z;
    int c0 = blockIdx.y * 32;
    int p0 = blockIdx.x * 32;
    int lp = threadIdx.x & 31;
    int cg = threadIdx.x >> 5;   // 0..7
    #pragma unroll
    for (int j = 0; j < 4; ++j) {
        int c = cg * 4 + j;
        tile[c][lp] = x[((size_t)b * 1024 + c0 + c) * PP + p0 + lp];
    }
    __syncthreads();
    #pragma unroll
    for (int j = 0; j < 4; ++j) {
        int rp = cg * 4 + j;
        xb[((size_t)b * PP + p0 + rp) * 1024 + c0 + lp] = __float2bfloat16(tile[lp][rp]);
    }
}

// w (Cout, Cin, 3, 3) f32 -> wb (9, Cout, Cin) bf16
__global__ void w3b_k(const float* __restrict__ w, bf16* __restrict__ wb, int Cout, int Cin) {
    int idx = blockIdx.x * 256 + threadIdx.x;
    int n = Cout * Cin * 9;
    if (idx >= n) return;
    int kk  = idx / (Cout * Cin);
    int rem = idx - kk * Cout * Cin;
    int co  = rem / Cin;
    int ci  = rem - co * Cin;
    wb[idx] = __float2bfloat16(w[((size_t)co * Cin + ci) * 9 + kk]);
}

// combined qkv weight assembly: q(32,256)+k(32,256)+v(256,256) f32 -> [320,256] bf16
__global__ void wqkv_k(const float* __restrict__ qw, const float* __restrict__ kw,
                       const float* __restrict__ vw, bf16* __restrict__ dst) {
    int idx = blockIdx.x * 256 + threadIdx.x;
    if (idx >= 320 * 256) return;
    int r = idx >> 8, c = idx & 255;
    float v = (r < 32) ? qw[r * 256 + c] : (r < 64) ? kw[(r - 32) * 256 + c]
                                                    : vw[(size_t)(r - 64) * 256 + c];
    dst[idx] = __float2bfloat16(v);
}

// combined qkv bias: [320] f32
__global__ void cb_k(const float* __restrict__ qb, const float* __restrict__ kb,
                     const float* __restrict__ vb, float* __restrict__ dst) {
    int i = threadIdx.x;   // 320
    dst[i] = (i < 32) ? qb[i] : (i < 64) ? kb[i - 32] : vb[i - 64];
}

// w (O, C) f32 -> wt (C, O) f32  (for cls GEMV)
__global__ void tw1_k(const float* __restrict__ w, float* __restrict__ wt, int O, int Cm) {
    int idx = blockIdx.x * 256 + threadIdx.x;
    int n = O * Cm;
    if (idx >= n) return;
    int o = idx / Cm;
    int c = idx - o * Cm;
    wt[c * O + o] = w[idx];
}

// ---------------- MFMA 3x3 conv, A-halo LDS reuse + global_load_lds staging ----------------
// r5-proven structure. r8: boundary masking moved from data (4 movs + exec per
// fragment) to a single address-select into zeroed LDS row 255. Rows 194-255
// are never read as data; the j==3,wv==3 DMA (rows 240-255) is skipped so the
// zero row survives all phases. LDS size unchanged (40 KB).
template<typename OutT>
__global__ __launch_bounds__(256, 2)
void mconv3_k(const bf16* __restrict__ in, const bf16* __restrict__ wt,
              const float* __restrict__ bias, OutT* __restrict__ out,
              int Cin, int CinT, int ciOff, int Cout, int accum) {
    __shared__ ushort As[256 * 32];   // halo rows M0-49..M0+206 (194 used) + zero row 255
    __shared__ ushort Bs[384 * 32];   // 3 taps x 128 cout rows
    const ushort* inu = (const ushort*)in;
    const ushort* wtu = (const ushort*)wt;
    int tid = threadIdx.x;
    int N0 = blockIdx.x * 128;
    int M0 = blockIdx.y * 96;
    int sr = tid >> 2;            // 0..63 (LDS row within segment)
    int sc = (tid & 3) * 8;       // 0,8,16,24 (linear LDS slot)
    int wv = tid >> 6, lane = tid & 63;
    int wm = (wv & 1) * 48, wn = (wv >> 1) * 64;
    int l15 = lane & 15, quad = lane >> 4;

    // zero row 255 (read target for invalid taps); never overwritten (j3/wv3 DMA skipped)
    if (tid < 4) {
        uint4 z; z.x = z.y = z.z = z.w = 0;
        *(uint4*)(As + 255 * 32 + tid * 8) = z;
    }

    // A staging: per-lane pre-swizzled global src, wave-uniform linear LDS dest
    const ushort* aptr[4];
    ushort* alds[4];
    #pragma unroll
    for (int j = 0; j < 4; ++j) {
        int row = j * 64 + sr;                         // LDS row
        int scs = sc ^ (((row >> 1) & 3) << 3);        // pre-swizzled col slot
        int gp = M0 - 49 + row;                        // global pixel row (clamped)
        gp = gp < 0 ? 0 : (gp > MM - 1 ? MM - 1 : gp);
        aptr[j] = inu + (size_t)gp * Cin + scs;
        alds[j] = As + (j * 64 + wv * 16) * 32;        // wave-uniform base
    }
    // B staging pointers for dy=0 taps; advance by dystep per dy
    const ushort* bptr[6];
    ushort* blds[6];
    #pragma unroll
    for (int j = 0; j < 6; ++j) {
        int row = j * 64 + sr;            // 0..383
        int scs = sc ^ (((row >> 1) & 3) << 3);
        int dxi = row >> 7;               // tap-within-dy 0..2
        int crow = row & 127;             // cout row within tile
        bptr[j] = wtu + ((size_t)dxi * Cout + N0 + crow) * CinT + ciOff + scs;
        blds[j] = Bs + (j * 64 + wv * 16) * 32;
    }
    size_t dystep = (size_t)3 * Cout * CinT;

    // per-lane (y,x) of the 3 A-rows this lane feeds to MFMA (fixed)
    int ry[3], rx[3];
    #pragma unroll
    for (int mi = 0; mi < 3; ++mi) {
        int r = (M0 + wm + mi * 16 + l15) % PP;
        ry[mi] = r / HHW;
        rx[mi] = r - ry[mi] * HHW;
    }

    f4 acc[3][4];
    #pragma unroll
    for (int i = 0; i < 3; ++i)
        #pragma unroll
        for (int j = 0; j < 4; ++j) acc[i][j] = (f4){0.f, 0.f, 0.f, 0.f};

    for (int c0 = 0; c0 < Cin; c0 += 32) {
        #pragma unroll
        for (int dy = 0; dy < 3; ++dy) {
            __syncthreads();                       // prior-phase readers done
            if (dy == 0) {
                #pragma unroll
                for (int j = 0; j < 4; ++j)
                    if (j < 3 || wv < 3)           // skip rows 240-255 (unused; keeps zero row)
                        gl_lds(aptr[j] + c0, alds[j]);
            }
            #pragma unroll
            for (int j = 0; j < 6; ++j)
                gl_lds(bptr[j] + dy * dystep + c0, blds[j]);
            __syncthreads();                       // drains vmcnt -> LDS visible
            int dyp = dy - 1;
            bool vy[3];
            #pragma unroll
            for (int mi = 0; mi < 3; ++mi) vy[mi] = (unsigned)(ry[mi] + dyp) < (unsigned)HHW;
            #pragma unroll
            for (int dxi = 0; dxi < 3; ++dxi) {
                int dxp = dxi - 1;
                int sh = 49 + dyp * HHW + dxp;     // LDS row shift for this tap
                bh8 af[3], bfr[4];
                #pragma unroll
                for (int mi = 0; mi < 3; ++mi) {
                    bool vld = vy[mi] && ((unsigned)(rx[mi] + dxp) < (unsigned)HHW);
                    int ad = vld ? loff(wm + mi * 16 + l15 + sh, quad * 8)
                                 : (255 * 32 + quad * 8);
                    af[mi] = *(const bh8*)(As + ad);
                }
                #pragma unroll
                for (int ni = 0; ni < 4; ++ni)
                    bfr[ni] = *(const bh8*)(Bs + loff(dxi * 128 + wn + ni * 16 + l15, quad * 8));
                #pragma unroll
                for (int mi = 0; mi < 3; ++mi)
                    #pragma unroll
                    for (int ni = 0; ni < 4; ++ni)
                        acc[mi][ni] = __builtin_amdgcn_mfma_f32_16x16x32_bf16(af[mi], bfr[ni], acc[mi][ni], 0, 0, 0);
            }
        }
    }

    // epilogue: C/D layout col=lane&15, row=quad*4+reg  [m89-verified]
    float bvn[4];
    #pragma unroll
    for (int ni = 0; ni < 4; ++ni)
        bvn[ni] = bias ? bias[N0 + wn + ni * 16 + l15] : 0.f;
    #pragma unroll
    for (int mi = 0; mi < 3; ++mi) {
        int mrow = M0 + wm + mi * 16 + quad * 4;
        #pragma unroll
        for (int ni = 0; ni < 4; ++ni) {
            int ncol = N0 + wn + ni * 16 + l15;
            #pragma unroll
            for (int r = 0; r < 4; ++r) {
                size_t oi = (size_t)(mrow + r) * Cout + ncol;
                float val = acc[mi][ni][r] + bvn[ni];
                if (accum) stf(&out[oi], ldf(&out[oi]) + val);
                else       stf(&out[oi], val);
            }
        }
    }
}

// ---------------- fused qkv MFMA GEMM: [36864,256] x [320,256]^T ----------------
// r8: M-tile 128 (2304 = 18*128, no staging waste; was 96 with 25% wasted A-DMA).
__global__ __launch_bounds__(256, 2)
void mqkv_k(const bf16* __restrict__ in, const bf16* __restrict__ wt,
            const float* __restrict__ bias, float* __restrict__ qo,
            float* __restrict__ ko, bf16* __restrict__ vo) {
    __shared__ ushort As[128 * 32];
    __shared__ ushort Bs[64 * 32];
    const int Cin = 256;
    const ushort* inu = (const ushort*)in;
    const ushort* wtu = (const ushort*)wt;
    int tid = threadIdx.x;
    int N0 = blockIdx.x * 64;       // 0..4 -> cols 0..319
    int M0 = blockIdx.y * 128;
    int sr = tid >> 2;
    int sc = (tid & 3) * 8;
    int scs = sc ^ (((sr >> 1) & 3) << 3);   // row ≡ sr (mod 64): swizzle bits match loff
    int wv = tid >> 6, lane = tid & 63;
    int wm = (wv & 1) * 64, wn = (wv >> 1) * 32;
    int l15 = lane & 15, quad = lane >> 4;

    const ushort* aptr[2];
    #pragma unroll
    for (int j = 0; j < 2; ++j)
        aptr[j] = inu + (size_t)(M0 + j * 64 + sr) * Cin + scs;
    const ushort* bptr = wtu + (size_t)(N0 + sr) * Cin + scs;
    ushort* alds0 = As + (wv * 16) * 32;
    ushort* alds1 = As + (64 + wv * 16) * 32;
    ushort* blds  = Bs + (wv * 16) * 32;

    f4 acc[4][2];
    #pragma unroll
    for (int i = 0; i < 4; ++i)
        #pragma unroll
        for (int j = 0; j < 2; ++j) acc[i][j] = (f4){0.f, 0.f, 0.f, 0.f};

    for (int c0 = 0; c0 < Cin; c0 += 32) {
        __syncthreads();
        gl_lds(aptr[0] + c0, alds0);
        gl_lds(aptr[1] + c0, alds1);
        gl_lds(bptr + c0, blds);
        __syncthreads();
        bh8 af[4], bfr[2];
        #pragma unroll
        for (int mi = 0; mi < 4; ++mi)
            af[mi] = *(const bh8*)(As + loff(wm + mi * 16 + l15, quad * 8));
        #pragma unroll
        for (int ni = 0; ni < 2; ++ni)
            bfr[ni] = *(const bh8*)(Bs + loff(wn + ni * 16 + l15, quad * 8));
        #pragma unroll
        for (int mi = 0; mi < 4; ++mi)
            #pragma unroll
            for (int ni = 0; ni < 2; ++ni)
                acc[mi][ni] = __builtin_amdgcn_mfma_f32_16x16x32_bf16(af[mi], bfr[ni], acc[mi][ni], 0, 0, 0);
    }

    float bvn[2];
    #pragma unroll
    for (int ni = 0; ni < 2; ++ni)
        bvn[ni] = bias[N0 + wn + ni * 16 + l15];
    #pragma unroll
    for (int mi = 0; mi < 4; ++mi) {
        int mrow = M0 + wm + mi * 16 + quad * 4;
        #pragma unroll
        for (int ni = 0; ni < 2; ++ni) {
            int ncol = N0 + wn + ni * 16 + l15;
            #pragma unroll
            for (int r = 0; r < 4; ++r) {
                float val = acc[mi][ni][r] + bvn[ni];
                if (ncol < 32)
                    qo[(size_t)(mrow + r) * 32 + ncol] = val;
                else if (ncol < 64)
                    ko[(size_t)(mrow + r) * 32 + ncol - 32] = val;
                else
                    vo[(size_t)(mrow + r) * 256 + ncol - 64] = __float2bfloat16(val);
            }
        }
    }
}

// ---------------- batch norm ----------------
__global__ void zero_k(float* p, int n) {
    int i = blockIdx.x * 256 + threadIdx.x;
    if (i < n) p[i] = 0.f;
}

template<typename S>
__global__ void bn_stats_k(const S* __restrict__ src, float* __restrict__ sum,
                           float* __restrict__ sumsq, int Cout) {
    int t  = threadIdx.x;
    int c  = blockIdx.x * 64 + (t & 63);
    int pl = t >> 6;
    int p0 = blockIdx.y * 1024;
    float s = 0.f, ss = 0.f;
    for (int i = pl; i < 1024; i += 4) {
        float v = ldf(&src[(size_t)(p0 + i) * Cout + c]);
        s += v; ss += v * v;
    }
    __shared__ float ls[256], lss[256];
    ls[t] = s; lss[t] = ss;
    __syncthreads();
    if (t < 64) {
        s  = ls[t]  + ls[t + 64]  + ls[t + 128]  + ls[t + 192];
        ss = lss[t] + lss[t + 64] + lss[t + 128] + lss[t + 192];
        atomicAdd(&sum[c], s);
        atomicAdd(&sumsq[c], ss);
    }
}

__global__ void bn_fin_k(const float* __restrict__ sum, const float* __restrict__ sumsq,
                         const float* __restrict__ g, const float* __restrict__ b,
                         float* __restrict__ scale, float* __restrict__ shift, int Cout) {
    int c = blockIdx.x * 256 + threadIdx.x;
    if (c >= Cout) return;
    const float invM = 1.f / 36864.f;
    float mean = sum[c] * invM;
    float var  = sumsq[c] * invM - mean * mean;
    float inv  = 1.f / sqrtf(var + 1e-5f);
    scale[c] = g[c] * inv;
    shift[c] = b[c] - mean * g[c] * inv;
}

template<typename S, typename D>
__global__ void bn_apply_k(const S* __restrict__ src, const float* __restrict__ scale,
                           const float* __restrict__ shift, D* __restrict__ dst,
                           int cmask, int n) {
    int idx = blockIdx.x * 256 + threadIdx.x;
    if (idx >= n) return;
    int c = idx & cmask;
    float y = ldf(&src[idx]) * scale[c] + shift[c];
    stf(&dst[idx], fmaxf(y, 0.f));
}

// ---------------- criss-cross spatial attention ----------------
__global__ void cc_logits_k(const float* __restrict__ q, const float* __restrict__ kk,
                            float* __restrict__ att) {
    int t = threadIdx.x;
    int p = blockIdx.x;
    int b = p / PP;
    int r = p - b * PP;
    int h = r / HHW;
    int w = r - h * HHW;
    __shared__ float qv[32];
    if (t < 32) qv[t] = q[p * 32 + t];
    __syncthreads();
    float val = -INFINITY;
    if (t < 48) {
        if (t != h) {
            const float4* kr4 = (const float4*)(kk + ((b * HHW + t) * HHW + w) * 32);
            float s = 0.f;
            #pragma unroll
            for (int c = 0; c < 8; ++c) {
                float4 kv = kr4[c];
                s += qv[c * 4 + 0] * kv.x + qv[c * 4 + 1] * kv.y
                   + qv[c * 4 + 2] * kv.z + qv[c * 4 + 3] * kv.w;
            }
            val = s;
        }
    } else if (t < 96) {
        const float4* kr4 = (const float4*)(kk + ((b * HHW + h) * HHW + (t - 48)) * 32);
        float s = 0.f;
        #pragma unroll
        for (int c = 0; c < 8; ++c) {
            float4 kv = kr4[c];
            s += qv[c * 4 + 0] * kv.x + qv[c * 4 + 1] * kv.y
               + qv[c * 4 + 2] * kv.z + qv[c * 4 + 3] * kv.w;
        }
        val = s;
    }
    __shared__ float red[128];
    red[t] = val;
    __syncthreads();
    for (int st = 64; st > 0; st >>= 1) { if (t < st) red[t] = fmaxf(red[t], red[t + st]); __syncthreads(); }
    float m = red[0];
    __syncthreads();
    float e = (t < 96 && val != -INFINITY) ? expf(val - m) : 0.f;
    red[t] = e;
    __syncthreads();
    for (int st = 64; st > 0; st >>= 1) { if (t < st) red[t] += red[t + st]; __syncthreads(); }
    float inv = 1.f / red[0];
    if (t < 96) att[p * 96 + t] = e * inv;
}

// oH pass: block (w, b). oH[b,h,w,c] = sum_g att[(b,h,w)][g] * v[(b,g,w)][c]
// v column-slice (48x256 bf16, 24 KB) + att slice staged in LDS -> each v row
// read once per block instead of once per pixel (was ~1.8 GB L2/dispatch).
__global__ void ccH_k(const float* __restrict__ att, const bf16* __restrict__ v,
                      bf16* __restrict__ tmp) {
    __shared__ ushort vs[48][256];
    __shared__ float as_[48][48];
    int w = blockIdx.x, b = blockIdx.y;
    int t = threadIdx.x;
    const ushort* vu = (const ushort*)v + ((size_t)b * PP + w) * 256;
    for (int i = t; i < 48 * 32; i += 256) {
        int g = i >> 5, c8 = (i & 31) * 8;
        *(bh8*)&vs[g][c8] = *(const bh8*)(vu + (size_t)g * HHW * 256 + c8);
    }
    for (int i = t; i < 48 * 48; i += 256) {
        int h = i / 48, g = i - h * 48;
        as_[h][g] = att[((size_t)(b * PP + h * HHW + w)) * 96 + g];
    }
    __syncthreads();
    int c2 = (t & 127) * 2;
    int h0 = (t >> 7) * 24;
    for (int hh = 0; hh < 24; ++hh) {
        int h = h0 + hh;
        float o0 = 0.f, o1 = 0.f;
        #pragma unroll 4
        for (int g = 0; g < 48; ++g) {
            float a = as_[h][g];
            unsigned u = *(const unsigned*)&vs[g][c2];
            o0 += a * b2f((ushort)u);
            o1 += a * b2f((ushort)(u >> 16));
        }
        unsigned* tp = (unsigned*)((ushort*)tmp + ((size_t)(b * PP + h * HHW + w)) * 256 + c2);
        *tp = (unsigned)f2bu(o0) | ((unsigned)f2bu(o1) << 16);
    }
}

// oW pass: block (h, b). oW[b,h,w,c] = sum_tt att[(b,h,w)][48+tt] * v[(b,h,tt)][c];
// adds tmp (oH) + residual, writes cc in-place.
__global__ void ccW_k(const float* __restrict__ att, const bf16* __restrict__ v,
                      const bf16* __restrict__ tmp, bf16* __restrict__ cc,
                      const float* __restrict__ gptr) {
    __shared__ ushort vs[48][256];
    __shared__ float as_[48][48];
    int h = blockIdx.x, b = blockIdx.y;
    int t = threadIdx.x;
    const ushort* vu = (const ushort*)v + ((size_t)b * PP + h * HHW) * 256;
    for (int i = t; i < 48 * 32; i += 256) {
        int tt = i >> 5, c8 = (i & 31) * 8;
        *(bh8*)&vs[tt][c8] = *(const bh8*)(vu + (size_t)tt * 256 + c8);
    }
    for (int i = t; i < 48 * 48; i += 256) {
        int w = i / 48, tt = i - w * 48;
        as_[w][tt] = att[((size_t)(b * PP + h * HHW + w)) * 96 + 48 + tt];
    }
    __syncthreads();
    float gamma = gptr[0];
    int c2 = (t & 127) * 2;
    int w0 = (t >> 7) * 24;
    for (int ww = 0; ww < 24; ++ww) {
        int w = w0 + ww;
        float o0 = 0.f, o1 = 0.f;
        #pragma unroll 4
        for (int tt = 0; tt < 48; ++tt) {
            float a = as_[w][tt];
            unsigned u = *(const unsigned*)&vs[tt][c2];
            o0 += a * b2f((ushort)u);
            o1 += a * b2f((ushort)(u >> 16));
        }
        size_t base = ((size_t)(b * PP + h * HHW + w)) * 256 + c2;
        unsigned ut = *(const unsigned*)((const ushort*)tmp + base);
        unsigned* cp = (unsigned*)((ushort*)cc + base);
        unsigned old = *cp;
        float r0 = gamma * (o0 + b2f((ushort)ut)) + b2f((ushort)old);
        float r1 = gamma * (o1 + b2f((ushort)(ut >> 16))) + b2f((ushort)(old >> 16));
        *cp = (unsigned)f2bu(r0) | ((unsigned)f2bu(r1) << 16);
    }
}

// ---------------- batch-grid ("my") attention ----------------
__global__ void gram_k(const float* __restrict__ q, const float* __restrict__ k,
                       float* __restrict__ G) {
    int t = threadIdx.x;
    int a  = blockIdx.x >> 4;
    int b2 = blockIdx.x & 15;
    const float* qa = q + a * 73728;
    const float* kb = k + b2 * 73728;
    float s = 0.f;
    for (int i = t; i < 73728; i += 256) s += qa[i] * kb[i];
    __shared__ float red[256];
    red[t] = s;
    __syncthreads();
    for (int st = 128; st > 0; st >>= 1) { if (t < st) red[t] += red[t + st]; __syncthreads(); }
    if (t == 0) G[blockIdx.x] = red[0];
}

__global__ void my_soft_k(const float* __restrict__ G, float* __restrict__ A) {
    int t = threadIdx.x;
    if (t >= 16) return;
    int i = t >> 2, j = t & 3;
    float l[8];
    for (int g = 0; g < 4; ++g) l[g] = (g == i) ? -INFINITY : G[t * 16 + g * 4 + j];
    for (int v = 0; v < 4; ++v) l[4 + v] = G[t * 16 + i * 4 + v];
    float m = l[0];
    for (int n = 1; n < 8; ++n) m = fmaxf(m, l[n]);
    float s = 0.f;
    for (int n = 0; n < 8; ++n) { l[n] = expf(l[n] - m); s += l[n]; }
    float inv = 1.f / s;
    for (int n = 0; n < 8; ++n) A[t * 8 + n] = l[n] * inv;
}

// bf16 v, 2 elements per thread (packed pair loads); grid 18432
__global__ void my_out_k(const float* __restrict__ A, const bf16* __restrict__ v,
                         bf16* __restrict__ my, const float* __restrict__ gptr) {
    int t = threadIdx.x;
    __shared__ float As[128];
    if (t < 128) As[t] = A[t];
    __syncthreads();
    size_t pidx = (size_t)blockIdx.x * 256 + t;   // pair index
    size_t idx = pidx * 2;
    int b = (int)(idx / 589824);
    int n = (int)(idx - (size_t)b * 589824);
    int i = b >> 2, j = b & 3;
    const ushort* vu = (const ushort*)v;
    float o0 = 0.f, o1 = 0.f;
    #pragma unroll
    for (int g = 0; g < 4; ++g) {
        unsigned u = *(const unsigned*)&vu[(size_t)(g * 4 + j) * 589824 + n];
        o0 += As[b * 8 + g] * b2f((ushort)u);
        o1 += As[b * 8 + g] * b2f((ushort)(u >> 16));
    }
    #pragma unroll
    for (int tt = 0; tt < 4; ++tt) {
        unsigned u = *(const unsigned*)&vu[(size_t)(i * 4 + tt) * 589824 + n];
        o0 += As[b * 8 + 4 + tt] * b2f((ushort)u);
        o1 += As[b * 8 + 4 + tt] * b2f((ushort)(u >> 16));
    }
    float gamma = gptr[0];
    unsigned* mp = (unsigned*)((ushort*)my + idx);
    unsigned old = *mp;
    float r0 = gamma * o0 + b2f((ushort)old);
    float r1 = gamma * o1 + b2f((ushort)(old >> 16));
    *mp = (unsigned)f2bu(r0) | ((unsigned)f2bu(r1) << 16);
}

// ---------------- classifier 1x1 -> f32 NCHW ----------------
__global__ void cls_k(const float* __restrict__ hsrc, const float* __restrict__ wt,
                      const float* __restrict__ bias, float* __restrict__ out) {
    int t = threadIdx.x;      // 128
    int p = blockIdx.x;
    __shared__ float hr[512];
    for (int i = t; i < 512; i += 128) hr[i] = hsrc[(size_t)p * 512 + i];
    __syncthreads();
    if (t < 21) {
        float acc = bias[t];
        #pragma unroll 4
        for (int c = 0; c < 512; ++c) acc += hr[c] * wt[c * 21 + t];
        int b = p / PP;
        int r = p - b * PP;
        out[(b * 21 + t) * PP + r] = acc;
    }
}

// ---------------- launch ----------------
extern "C" void kernel_launch(void* const* d_in, const int* in_sizes, int n_in,
                              void* d_out, int out_size, void* d_ws, size_t ws_size,
                              hipStream_t stream) {
    const float* x     = (const float*)d_in[0];
    const float* w_a   = (const float*)d_in[1];
    const float* g_a   = (const float*)d_in[2];
    const float* b_a   = (const float*)d_in[3];
    const float* ccq_w = (const float*)d_in[4];
    const float* ccq_b = (const float*)d_in[5];
    const float* cck_w = (const float*)d_in[6];
    const float* cck_b = (const float*)d_in[7];
    const float* ccv_w = (const float*)d_in[8];
    const float* ccv_b = (const float*)d_in[9];
    const float* cc_g  = (const float*)d_in[10];
    const float* w_b   = (const float*)d_in[11];
    const float* g_b   = (const float*)d_in[12];
    const float* b_b   = (const float*)d_in[13];
    const float* w_m1  = (const float*)d_in[14];
    const float* g_m1  = (const float*)d_in[15];
    const float* b_m1  = (const float*)d_in[16];
    const float* myq_w = (const float*)d_in[17];
    const float* myq_b = (const float*)d_in[18];
    const float* myk_w = (const float*)d_in[19];
    const float* myk_b = (const float*)d_in[20];
    const float* myv_w = (const float*)d_in[21];
    const float* myv_b = (const float*)d_in[22];
    const float* my_g  = (const float*)d_in[23];
    const float* w_m2  = (const float*)d_in[24];
    const float* g_m2  = (const float*)d_in[25];
    const float* b_m2  = (const float*)d_in[26];
    const float* w_c   = (const float*)d_in[27];
    const float* g_c   = (const float*)d_in[28];
    const float* b_c   = (const float*)d_in[29];
    const float* w_cls = (const float*)d_in[30];
    const float* b_cls = (const float*)d_in[31];
    float* out = (float*)d_out;

    char* ws = (char*)d_ws;
    size_t off = 0;
    bf16* cc  = (bf16*)(ws + off); off += (size_t)MM * 256 * 2;     // 18,874,368
    bf16* my  = (bf16*)(ws + off); off += (size_t)MM * 256 * 2;
    char* hx  = ws + off;          off += (size_t)MM * 256 * 4;     // 37,748,736 (f32 256 OR bf16 512)
    char* B   = ws + off;          off += (size_t)MM * 512 * 4;     // 75,497,472 multi-use
    bf16* wab  = (bf16*)(ws + off); off += 4718592;
    bf16* wm1b = (bf16*)(ws + off); off += 4718592;
    bf16* wbb  = (bf16*)(ws + off); off += 1179648;
    bf16* wm2b = (bf16*)(ws + off); off += 1179648;
    bf16* wcb  = (bf16*)(ws + off); off += 14155776;
    bf16* wqc  = (bf16*)(ws + off); off += 163840;    // cc qkv combined [320,256] bf16
    bf16* wqm  = (bf16*)(ws + off); off += 163840;    // my qkv combined
    float* wclsT = (float*)(ws + off); off += 43008;
    float* stats = (float*)(ws + off); off += 16384;
    if (ws_size < off) return;   // ~177.4 MB
    float* ssum   = stats;
    float* ssumsq = stats + 512;
    float* sscale = stats + 1024;
    float* sshift = stats + 1536;
    float* G = stats + 2048;
    float* A = stats + 2048 + 256;
    float* bqc = stats + 2560;   // [320] combined cc bias
    float* bqm = stats + 2880;   // [320] combined my bias

    // region B sub-views
    bf16*  xbf = (bf16*)B;                           // [36864,1024] early
    float* qb  = (float*)B;                          // attention phase [36864,32] f32
    float* kb  = (float*)(B + 4718592);
    bf16*  vbb = (bf16*)(B + 9437184);               // [36864,256] bf16, ends 28,311,552
    bf16*  tmpH = (bf16*)(B + 28311552);             // [36864,256] bf16 oH scratch, ends 47,185,920
    float* att = (float*)(B + 47185920);             // [36864,96]  f32
    float* hxf = (float*)hx;                         // conv scratch f32 [36864,256]
    bf16*  hxb = (bf16*)hx;                          // concat accum bf16 [36864,512]
    float* hfin = (float*)B;                         // final BN output f32 [36864,512]

    // ---- prep ----
    x2b_k<<<dim3(72, 32, 16), 256, 0, stream>>>(x, xbf);
    w3b_k<<<9216, 256, 0, stream>>>(w_a,  wab,  256, 1024);
    w3b_k<<<9216, 256, 0, stream>>>(w_m1, wm1b, 256, 1024);
    w3b_k<<<2304, 256, 0, stream>>>(w_b,  wbb,  256, 256);
    w3b_k<<<2304, 256, 0, stream>>>(w_m2, wm2b, 256, 256);
    w3b_k<<<27648, 256, 0, stream>>>(w_c, wcb,  512, 1536);
    wqkv_k<<<320, 256, 0, stream>>>(ccq_w, cck_w, ccv_w, wqc);
    wqkv_k<<<320, 256, 0, stream>>>(myq_w, myk_w, myv_w, wqm);
    cb_k<<<1, 320, 0, stream>>>(ccq_b, cck_b, ccv_b, bqc);
    cb_k<<<1, 320, 0, stream>>>(myq_b, myk_b, myv_b, bqm);
    tw1_k<<<42, 256, 0, stream>>>(w_cls, wclsT, 21, 512);

    auto bn = [&](auto* src, const float* g, const float* b, auto* dst, int Cout) {
        zero_k<<<4, 256, 0, stream>>>(ssum, 1024);
        bn_stats_k<<<dim3(Cout / 64, 36), 256, 0, stream>>>(src, ssum, ssumsq, Cout);
        bn_fin_k<<<(Cout + 255) / 256, 256, 0, stream>>>(ssum, ssumsq, g, b, sscale, sshift, Cout);
        int n = MM * Cout;
        bn_apply_k<<<n / 256, 256, 0, stream>>>(src, sscale, sshift, dst, Cout - 1, n);
    };

    // ---- initial convs (read xbf in B) ----
    mconv3_k<float><<<dim3(2, 384), 256, 0, stream>>>(xbf, wab, nullptr, hxf, 1024, 1024, 0, 256, 0);
    bn(hxf, g_a, b_a, cc, 256);
    mconv3_k<float><<<dim3(2, 384), 256, 0, stream>>>(xbf, wm1b, nullptr, hxf, 1024, 1024, 0, 256, 0);
    bn(hxf, g_m1, b_m1, my, 256);
    // concat x-part now (before B is reused): -> hx as bf16 [36864,512]
    mconv3_k<bf16><<<dim3(4, 384), 256, 0, stream>>>(xbf, wcb, nullptr, hxb, 1024, 1536, 0, 512, 0);

    // ---- criss-cross spatial attention x2 (bf16 cc in-place) ----
    for (int rec = 0; rec < 2; ++rec) {
        mqkv_k<<<dim3(5, 288), 256, 0, stream>>>(cc, wqc, bqc, qb, kb, vbb);
        cc_logits_k<<<MM, 128, 0, stream>>>(qb, kb, att);
        ccH_k<<<dim3(48, 16), 256, 0, stream>>>(att, vbb, tmpH);
        ccW_k<<<dim3(48, 16), 256, 0, stream>>>(att, vbb, tmpH, cc, cc_g);
    }

    // ---- batch-grid attention x2 (bf16 my in-place) ----
    for (int rec = 0; rec < 2; ++rec) {
        mqkv_k<<<dim3(5, 288), 256, 0, stream>>>(my, wqm, bqm, qb, kb, vbb);
        gram_k<<<256, 256, 0, stream>>>(qb, kb, G);
        my_soft_k<<<1, 64, 0, stream>>>(G, A);
        my_out_k<<<18432, 256, 0, stream>>>(A, vbb, my, my_g);
    }

    // ---- post convs (outputs -> B as f32 scratch; B attention data dead) ----
    float* pscr = (float*)B;
    mconv3_k<float><<<dim3(2, 384), 256, 0, stream>>>(cc, wbb, nullptr, pscr, 256, 256, 0, 256, 0);
    bn(pscr, g_b, b_b, cc, 256);
    mconv3_k<float><<<dim3(2, 384), 256, 0, stream>>>(my, wm2b, nullptr, pscr, 256, 256, 0, 256, 0);
    bn(pscr, g_m2, b_m2, my, 256);

    // ---- concat cc/my parts accumulate into hxb ----
    mconv3_k<bf16><<<dim3(4, 384), 256, 0, stream>>>(cc, wcb, nullptr, hxb, 256, 1536, 1024, 512, 1);
    mconv3_k<bf16><<<dim3(4, 384), 256, 0, stream>>>(my, wcb, nullptr, hxb, 256, 1536, 1280, 512, 1);
    bn(hxb, g_c, b_c, hfin, 512);

    // ---- classifier ----
    cls_k<<<MM, 128, 0, stream>>>(hfin, wclsT, b_cls, out);
}